// Round 2
// baseline (882.207 us; speedup 1.0000x reference)
//
#include <hip/hip_runtime.h>
#include <math.h>

__device__ __forceinline__ float sspf(float x) {
    return __logf(1.0f + __expf(x)) - 0.6931471805599453f;
}

__device__ __forceinline__ float rlane(float v, int l) {
    return __uint_as_float(__builtin_amdgcn_readlane(__float_as_uint(v), l));
}

constexpr float INV_M      = 0.17677669529663687f;   // 1/sqrt(32)
constexpr float INV_R      = 0.25f;                  // 1/sqrt(16)
constexpr float INV_H      = 0.125f;                 // 1/sqrt(64)
constexpr float INV_2M_DEG = 0.125f * 0.17677669529663687f; // 1/sqrt(64)*1/sqrt(32)
constexpr float INV_FAN    = 0.0625f;                // 1/sqrt(32*8)
constexpr float INV_SQRT3  = 0.5773502691896258f;

// ---------------- Kernel A: linear_1 ----------------
__global__ __launch_bounds__(256) void k_lin1(
    const float* __restrict__ node_s, const float* __restrict__ node_v,
    const float* __restrict__ W1s, const float* __restrict__ W1v,
    float* __restrict__ s_ws, float* __restrict__ v_ws, int N)
{
    __shared__ float sWs[1024], sWv[1024];
    for (int i = threadIdx.x; i < 1024; i += 256) {
        sWs[i] = W1s[i] * INV_M;
        sWv[i] = W1v[i] * INV_M;
    }
    __syncthreads();
    int j = threadIdx.x & 31;
    int n = blockIdx.x * 8 + (threadIdx.x >> 5);
    if (n >= N) return;
    const float* ss = node_s + (size_t)n * 32;
    const float* vv = node_v + (size_t)n * 96;
    float as = 0.f, a0 = 0.f, a1 = 0.f, a2 = 0.f;
    #pragma unroll
    for (int u = 0; u < 32; ++u) {
        float ws_ = sWs[u * 32 + j];
        float wv_ = sWv[u * 32 + j];
        as = fmaf(ss[u], ws_, as);
        a0 = fmaf(vv[u * 3 + 0], wv_, a0);
        a1 = fmaf(vv[u * 3 + 1], wv_, a1);
        a2 = fmaf(vv[u * 3 + 2], wv_, a2);
    }
    s_ws[(size_t)n * 32 + j] = as;
    v_ws[(size_t)n * 96 + j] = a0;
    v_ws[(size_t)n * 96 + 32 + j] = a1;
    v_ws[(size_t)n * 96 + 64 + j] = a2;
}

// ---------------- CSR build ----------------
__global__ __launch_bounds__(256) void k_hist(
    const int* __restrict__ eidx, int* __restrict__ count, int E)
{
    int e = blockIdx.x * 256 + threadIdx.x;
    if (e < E) atomicAdd(&count[eidx[E + e]], 1);
}

// single wave: exclusive scan of count[0..N) -> row_off[0..N], copy into cursor
__global__ __launch_bounds__(64) void k_scan(
    const int* __restrict__ count, int* __restrict__ row_off,
    int* __restrict__ cursor, int N)
{
    int t = threadIdx.x;
    int chunk = (N + 63) / 64;
    int lo = t * chunk, hi = min(N, lo + chunk);
    int s = 0;
    for (int i = lo; i < hi; ++i) s += count[i];
    int x = s;
    #pragma unroll
    for (int off = 1; off < 64; off <<= 1) {
        int y = __shfl_up(x, off, 64);
        if (t >= off) x += y;
    }
    int run = x - s;  // exclusive prefix
    for (int i = lo; i < hi; ++i) {
        int c = count[i];
        row_off[i] = run;
        cursor[i] = run;
        run += c;
    }
    if (t == 63) row_off[N] = run;
}

__global__ __launch_bounds__(256) void k_fill(
    const int* __restrict__ eidx, int* __restrict__ cursor,
    int* __restrict__ elist, int E)
{
    int e = blockIdx.x * 256 + threadIdx.x;
    if (e < E) {
        int slot = atomicAdd(&cursor[eidx[E + e]], 1);
        elist[slot] = e;
    }
}

// ---------------- Kernel B: per-node gather + radial MLP + CG TP ----------------
// One wave per destination node. No atomics.
// Lane j<32 owns channel j of paths (w1: 0e x 0e, w2: 0e x 1o);
// lane 32+u owns channel u of paths (w4: 1o x 1o, w3: 1o x 0e).
__global__ __launch_bounds__(256) void k_agg(
    const float* __restrict__ edge_emb, const float* __restrict__ edge_y0,
    const float* __restrict__ edge_y1, const int* __restrict__ edge_index,
    const float* __restrict__ Wr1, const float* __restrict__ Wr2,
    const float* __restrict__ s_ws, const float* __restrict__ v_ws,
    const int* __restrict__ row_off, const int* __restrict__ elist,
    float* __restrict__ agg_s, float* __restrict__ agg_v, int N, int E)
{
    // Wr2 staged as k-pair quads: q=(k>>1), lane j -> {W[k][j],W[k][64+j],W[k+1][j],W[k+1][64+j]}*INV_H
    __shared__ float sW2[8192];
    for (int idx = threadIdx.x; idx < 8192; idx += 256) {
        int c = idx & 3, j = (idx >> 2) & 63, q = idx >> 8;
        int k = 2 * q + (c >> 1);
        int col = j + ((c & 1) << 6);
        sW2[idx] = Wr2[k * 128 + col] * INV_H;
    }
    __syncthreads();

    int lane = threadIdx.x & 63;
    float wr1[16];
    #pragma unroll
    for (int k = 0; k < 16; ++k) wr1[k] = Wr1[k * 64 + lane] * INV_R;

    const float4* w2q = (const float4*)sW2;

    int n = blockIdx.x * 4 + ((threadIdx.x >> 6));
    if (n >= N) return;
    int row = row_off[n], end = row_off[n + 1];

    float accs = 0.f, acc0 = 0.f, acc1 = 0.f, acc2 = 0.f;
    int u = lane & 31;
    bool low = (lane < 32);

    for (int i = row; i < end; i += 2) {
        int eA = elist[i];
        bool hasB = (i + 1 < end);
        int eB = hasB ? elist[i + 1] : eA;

        // ---- layer 1 for both edges ----
        const float4* embA = (const float4*)(edge_emb + (size_t)eA * 16);
        const float4* embB = (const float4*)(edge_emb + (size_t)eB * 16);
        float4 a0 = embA[0], a1 = embA[1], a2 = embA[2], a3 = embA[3];
        float4 b0 = embB[0], b1 = embB[1], b2 = embB[2], b3 = embB[3];
        float xA = a0.x * wr1[0];
        xA = fmaf(a0.y, wr1[1], xA);  xA = fmaf(a0.z, wr1[2], xA);  xA = fmaf(a0.w, wr1[3], xA);
        xA = fmaf(a1.x, wr1[4], xA);  xA = fmaf(a1.y, wr1[5], xA);  xA = fmaf(a1.z, wr1[6], xA);
        xA = fmaf(a1.w, wr1[7], xA);  xA = fmaf(a2.x, wr1[8], xA);  xA = fmaf(a2.y, wr1[9], xA);
        xA = fmaf(a2.z, wr1[10], xA); xA = fmaf(a2.w, wr1[11], xA); xA = fmaf(a3.x, wr1[12], xA);
        xA = fmaf(a3.y, wr1[13], xA); xA = fmaf(a3.z, wr1[14], xA); xA = fmaf(a3.w, wr1[15], xA);
        float xB = b0.x * wr1[0];
        xB = fmaf(b0.y, wr1[1], xB);  xB = fmaf(b0.z, wr1[2], xB);  xB = fmaf(b0.w, wr1[3], xB);
        xB = fmaf(b1.x, wr1[4], xB);  xB = fmaf(b1.y, wr1[5], xB);  xB = fmaf(b1.z, wr1[6], xB);
        xB = fmaf(b1.w, wr1[7], xB);  xB = fmaf(b2.x, wr1[8], xB);  xB = fmaf(b2.y, wr1[9], xB);
        xB = fmaf(b2.z, wr1[10], xB); xB = fmaf(b2.w, wr1[11], xB); xB = fmaf(b3.x, wr1[12], xB);
        xB = fmaf(b3.y, wr1[13], xB); xB = fmaf(b3.z, wr1[14], xB); xB = fmaf(b3.w, wr1[15], xB);
        float hA = sspf(xA);
        float hB = sspf(xB);

        // ---- layer 2: readlane broadcast + shared weight quad loads ----
        float waA = 0.f, wbA = 0.f, waB = 0.f, wbB = 0.f;
        #pragma unroll
        for (int q = 0; q < 32; ++q) {
            float4 ww = w2q[q * 64 + lane];
            float hA0 = rlane(hA, 2 * q), hA1 = rlane(hA, 2 * q + 1);
            float hB0 = rlane(hB, 2 * q), hB1 = rlane(hB, 2 * q + 1);
            waA = fmaf(hA0, ww.x, waA); wbA = fmaf(hA0, ww.y, wbA);
            waA = fmaf(hA1, ww.z, waA); wbA = fmaf(hA1, ww.w, wbA);
            waB = fmaf(hB0, ww.x, waB); wbB = fmaf(hB0, ww.y, wbB);
            waB = fmaf(hB1, ww.z, waB); wbB = fmaf(hB1, ww.w, wbB);
        }

        // ---- tensor product + accumulate: edge A ----
        {
            int src = edge_index[eA];
            float y0e = edge_y0[eA];
            float y1x = edge_y1[(size_t)eA * 3];
            float y1y = edge_y1[(size_t)eA * 3 + 1];
            float y1z = edge_y1[(size_t)eA * 3 + 2];
            const float* sp = s_ws + (size_t)src * 32;
            const float* vp = v_ws + (size_t)src * 96;
            float se = sp[u];
            float vx = vp[u], vy = vp[32 + u], vz = vp[64 + u];
            float dot = vx * y1x + vy * y1y + vz * y1z;
            float wXa = __shfl_xor(waA, 32, 64);
            float wXb = __shfl_xor(wbA, 32, 64);
            accs += low ? (waA * se * y0e) : (wbA * dot * INV_SQRT3);
            if (low) {
                float t = wXa * se;
                acc0 = fmaf(t, y1x, acc0); acc1 = fmaf(t, y1y, acc1); acc2 = fmaf(t, y1z, acc2);
            } else {
                float t = wXb * y0e;
                acc0 = fmaf(t, vx, acc0); acc1 = fmaf(t, vy, acc1); acc2 = fmaf(t, vz, acc2);
            }
        }
        // ---- tensor product + accumulate: edge B ----
        if (hasB) {
            int src = edge_index[eB];
            float y0e = edge_y0[eB];
            float y1x = edge_y1[(size_t)eB * 3];
            float y1y = edge_y1[(size_t)eB * 3 + 1];
            float y1z = edge_y1[(size_t)eB * 3 + 2];
            const float* sp = s_ws + (size_t)src * 32;
            const float* vp = v_ws + (size_t)src * 96;
            float se = sp[u];
            float vx = vp[u], vy = vp[32 + u], vz = vp[64 + u];
            float dot = vx * y1x + vy * y1y + vz * y1z;
            float wXa = __shfl_xor(waB, 32, 64);
            float wXb = __shfl_xor(wbB, 32, 64);
            accs += low ? (waB * se * y0e) : (wbB * dot * INV_SQRT3);
            if (low) {
                float t = wXa * se;
                acc0 = fmaf(t, y1x, acc0); acc1 = fmaf(t, y1y, acc1); acc2 = fmaf(t, y1z, acc2);
            } else {
                float t = wXb * y0e;
                acc0 = fmaf(t, vx, acc0); acc1 = fmaf(t, vy, acc1); acc2 = fmaf(t, vz, acc2);
            }
        }
    }

    agg_s[(size_t)n * 64 + lane] = accs;
    agg_v[(size_t)n * 192 + lane] = acc0;
    agg_v[(size_t)n * 192 + 64 + lane] = acc1;
    agg_v[(size_t)n * 192 + 128 + lane] = acc2;
}

// ---------------- Kernel C: linear_2 + self-connection + output ----------------
__global__ __launch_bounds__(256) void k_out(
    const float* __restrict__ node_s, const float* __restrict__ node_v,
    const float* __restrict__ attrs,
    const float* __restrict__ agg_s, const float* __restrict__ agg_v,
    const float* __restrict__ W2s, const float* __restrict__ W2v,
    const float* __restrict__ Wscs, const float* __restrict__ Wscv,
    float* __restrict__ out, int N)
{
    __shared__ float sW2s[2048], sW2v[2048], sCs[8192], sCv[8192];
    for (int i = threadIdx.x; i < 2048; i += 256) {
        sW2s[i] = W2s[i] * INV_2M_DEG;
        sW2v[i] = W2v[i] * INV_2M_DEG;
    }
    for (int i = threadIdx.x; i < 8192; i += 256) {
        sCs[i] = Wscs[i] * INV_FAN;
        sCv[i] = Wscv[i] * INV_FAN;
    }
    __syncthreads();
    int j = threadIdx.x & 31;
    int n = blockIdx.x * 8 + (threadIdx.x >> 5);
    if (n >= N) return;

    float at[8];
    #pragma unroll
    for (int a = 0; a < 8; ++a) at[a] = attrs[(size_t)n * 8 + a];

    float os = 0.f, o0 = 0.f, o1 = 0.f, o2 = 0.f;
    const float* ags = agg_s + (size_t)n * 64;
    const float* agv = agg_v + (size_t)n * 192;
    #pragma unroll
    for (int u = 0; u < 64; ++u) {
        float w2s = sW2s[u * 32 + j];
        float w2v = sW2v[u * 32 + j];
        os = fmaf(ags[u], w2s, os);
        o0 = fmaf(agv[u], w2v, o0);
        o1 = fmaf(agv[64 + u], w2v, o1);
        o2 = fmaf(agv[128 + u], w2v, o2);
    }

    const float* sn = node_s + (size_t)n * 32;
    const float* vn = node_v + (size_t)n * 96;
    #pragma unroll 4
    for (int u = 0; u < 32; ++u) {
        float su = sn[u];
        float v0 = vn[u * 3], v1 = vn[u * 3 + 1], v2 = vn[u * 3 + 2];
        #pragma unroll
        for (int a = 0; a < 8; ++a) {
            float ca = at[a];
            float wcs = sCs[(u * 8 + a) * 32 + j];
            float wcv = sCv[(u * 8 + a) * 32 + j];
            os = fmaf(su * ca, wcs, os);
            float t = ca * wcv;
            o0 = fmaf(v0, t, o0);
            o1 = fmaf(v1, t, o1);
            o2 = fmaf(v2, t, o2);
        }
    }

    float* op = out + (size_t)n * 128;
    op[j] = os;
    op[32 + j * 3 + 0] = o0;
    op[32 + j * 3 + 1] = o1;
    op[32 + j * 3 + 2] = o2;
}

extern "C" void kernel_launch(void* const* d_in, const int* in_sizes, int n_in,
                              void* d_out, int out_size, void* d_ws, size_t ws_size,
                              hipStream_t stream)
{
    const float* node_s = (const float*)d_in[0];
    const float* node_v = (const float*)d_in[1];
    const float* attrs  = (const float*)d_in[2];
    const float* emb    = (const float*)d_in[3];
    const float* y0     = (const float*)d_in[4];
    const float* y1     = (const float*)d_in[5];
    const int*   eidx   = (const int*)d_in[6];
    const float* W1s  = (const float*)d_in[7];
    const float* W1v  = (const float*)d_in[8];
    const float* Wr1  = (const float*)d_in[9];
    const float* Wr2  = (const float*)d_in[10];
    const float* W2s  = (const float*)d_in[11];
    const float* W2v  = (const float*)d_in[12];
    const float* Wscs = (const float*)d_in[13];
    const float* Wscv = (const float*)d_in[14];

    int N = in_sizes[0] / 32;   // 20000
    int E = in_sizes[3] / 16;   // 640000

    float* ws    = (float*)d_ws;
    float* s_ws  = ws;                              // N*32
    float* v_ws  = s_ws + (size_t)N * 32;           // N*96
    float* agg_s = v_ws + (size_t)N * 96;           // N*64
    float* agg_v = agg_s + (size_t)N * 64;          // N*192
    int*   count   = (int*)(agg_v + (size_t)N * 192); // N
    int*   row_off = count + N;                       // N+1
    int*   cursor  = row_off + (N + 1);               // N
    int*   elist   = cursor + N;                      // E

    hipMemsetAsync(count, 0, (size_t)N * sizeof(int), stream);

    k_lin1<<<dim3((N + 7) / 8), dim3(256), 0, stream>>>(node_s, node_v, W1s, W1v, s_ws, v_ws, N);
    k_hist<<<dim3((E + 255) / 256), dim3(256), 0, stream>>>(eidx, count, E);
    k_scan<<<dim3(1), dim3(64), 0, stream>>>(count, row_off, cursor, N);
    k_fill<<<dim3((E + 255) / 256), dim3(256), 0, stream>>>(eidx, cursor, elist, E);
    k_agg<<<dim3((N + 3) / 4), dim3(256), 0, stream>>>(emb, y0, y1, eidx, Wr1, Wr2,
                                                       s_ws, v_ws, row_off, elist,
                                                       agg_s, agg_v, N, E);
    k_out<<<dim3((N + 7) / 8), dim3(256), 0, stream>>>(node_s, node_v, attrs, agg_s, agg_v,
                                                       W2s, W2v, Wscs, Wscv, (float*)d_out, N);
}

// Round 3
// 725.254 us; speedup vs baseline: 1.2164x; 1.2164x over previous
//
#include <hip/hip_runtime.h>
#include <hip/hip_bf16.h>
#include <math.h>

__device__ __forceinline__ float sspf(float x) {
    return __logf(1.0f + __expf(x)) - 0.6931471805599453f;
}

__device__ __forceinline__ float rlane(float v, int l) {
    return __uint_as_float(__builtin_amdgcn_readlane(__float_as_uint(v), l));
}

// w-buffer storage helpers (fp32 preferred, bf16 fallback if workspace is small)
__device__ __forceinline__ void wstore(float* p, float v) { *p = v; }
__device__ __forceinline__ void wstore(__hip_bfloat16* p, float v) { *p = __float2bfloat16(v); }
__device__ __forceinline__ float wload(const float* p) { return *p; }
__device__ __forceinline__ float wload(const __hip_bfloat16* p) { return __bfloat162float(*p); }

constexpr float INV_M      = 0.17677669529663687f;   // 1/sqrt(32)
constexpr float INV_R      = 0.25f;                  // 1/sqrt(16)
constexpr float INV_H      = 0.125f;                 // 1/sqrt(64)
constexpr float INV_2M_DEG = 0.125f * 0.17677669529663687f; // 1/sqrt(64)*1/sqrt(32)
constexpr float INV_FAN    = 0.0625f;                // 1/sqrt(32*8)
constexpr float INV_SQRT3  = 0.5773502691896258f;

// ---------------- Kernel A: linear_1 ----------------
__global__ __launch_bounds__(256) void k_lin1(
    const float* __restrict__ node_s, const float* __restrict__ node_v,
    const float* __restrict__ W1s, const float* __restrict__ W1v,
    float* __restrict__ s_ws, float* __restrict__ v_ws, int N)
{
    __shared__ float sWs[1024], sWv[1024];
    for (int i = threadIdx.x; i < 1024; i += 256) {
        sWs[i] = W1s[i] * INV_M;
        sWv[i] = W1v[i] * INV_M;
    }
    __syncthreads();
    int j = threadIdx.x & 31;
    int n = blockIdx.x * 8 + (threadIdx.x >> 5);
    if (n >= N) return;
    const float* ss = node_s + (size_t)n * 32;
    const float* vv = node_v + (size_t)n * 96;
    float as = 0.f, a0 = 0.f, a1 = 0.f, a2 = 0.f;
    #pragma unroll
    for (int u = 0; u < 32; ++u) {
        float ws_ = sWs[u * 32 + j];
        float wv_ = sWv[u * 32 + j];
        as = fmaf(ss[u], ws_, as);
        a0 = fmaf(vv[u * 3 + 0], wv_, a0);
        a1 = fmaf(vv[u * 3 + 1], wv_, a1);
        a2 = fmaf(vv[u * 3 + 2], wv_, a2);
    }
    s_ws[(size_t)n * 32 + j] = as;
    v_ws[(size_t)n * 96 + j] = a0;
    v_ws[(size_t)n * 96 + 32 + j] = a1;
    v_ws[(size_t)n * 96 + 64 + j] = a2;
}

// ---------------- CSR build ----------------
__global__ __launch_bounds__(256) void k_hist(
    const int* __restrict__ eidx, int* __restrict__ count, int E)
{
    int e = blockIdx.x * 256 + threadIdx.x;
    if (e < E) atomicAdd(&count[eidx[E + e]], 1);
}

// one block of 1024 threads: exclusive scan of count[0..N) -> row_off[0..N] + cursor
__global__ __launch_bounds__(1024) void k_scan(
    const int* __restrict__ count, int* __restrict__ row_off,
    int* __restrict__ cursor, int N)
{
    __shared__ int wsum[16], woff[16];
    int tid = threadIdx.x;
    int per = (N + 1023) / 1024;
    int base = tid * per;
    int lim = min(N, base + per);
    int s = 0;
    for (int i = base; i < lim; ++i) s += count[i];
    int lane = tid & 63, wv = tid >> 6;
    int x = s;
    #pragma unroll
    for (int off = 1; off < 64; off <<= 1) {
        int y = __shfl_up(x, off, 64);
        if (lane >= off) x += y;
    }
    if (lane == 63) wsum[wv] = x;
    __syncthreads();
    if (wv == 0 && lane < 16) {
        int t = wsum[lane];
        int xx = t;
        #pragma unroll
        for (int off = 1; off < 16; off <<= 1) {
            int y = __shfl_up(xx, off, 64);
            if (lane >= off) xx += y;
        }
        woff[lane] = xx - t;
        if (lane == 15) row_off[N] = xx;
    }
    __syncthreads();
    int run = x - s + woff[wv];   // exclusive prefix for this thread's segment
    for (int i = base; i < lim; ++i) {
        int c = count[i];
        row_off[i] = run;
        cursor[i] = run;
        run += c;
    }
}

// fill edge list in CSR order + pack per-slot metadata {y1.x, y1.y, y1.z, y0} and src
__global__ __launch_bounds__(256) void k_fill(
    const int* __restrict__ eidx, const float* __restrict__ y0,
    const float* __restrict__ y1, int* __restrict__ cursor,
    int* __restrict__ elist, float4* __restrict__ pk,
    int* __restrict__ srcs, int E)
{
    int e = blockIdx.x * 256 + threadIdx.x;
    if (e < E) {
        int slot = atomicAdd(&cursor[eidx[E + e]], 1);
        elist[slot] = e;
        srcs[slot] = eidx[e];
        pk[slot] = make_float4(y1[(size_t)e * 3], y1[(size_t)e * 3 + 1],
                               y1[(size_t)e * 3 + 2], y0[e]);
    }
}

// ---------------- Kernel B1: radial MLP, slot-ordered, edge-parallel ----------------
// Wave per 2 slots. Lane j computes w[j] (wa) and w[64+j] (wb). Sequential w writes.
template <typename WT>
__global__ __launch_bounds__(256) void k_mlp(
    const float* __restrict__ edge_emb, const int* __restrict__ elist,
    const float* __restrict__ Wr1, const float* __restrict__ Wr2,
    WT* __restrict__ w_s, int E)
{
    // Wr2 staged as k-pair quads: lane j, q -> {W[2q][j],W[2q][64+j],W[2q+1][j],W[2q+1][64+j]}*INV_H
    __shared__ float sW2[8192];
    for (int idx = threadIdx.x; idx < 8192; idx += 256) {
        int c = idx & 3, j = (idx >> 2) & 63, q = idx >> 8;
        int k = 2 * q + (c >> 1);
        int col = j + ((c & 1) << 6);
        sW2[idx] = Wr2[k * 128 + col] * INV_H;
    }
    __syncthreads();

    int lane = threadIdx.x & 63;
    float wr1[16];
    #pragma unroll
    for (int k = 0; k < 16; ++k) wr1[k] = Wr1[k * 64 + lane] * INV_R;

    const float4* w2q = (const float4*)sW2;
    int wid = (blockIdx.x * 256 + threadIdx.x) >> 6;
    int nw  = (gridDim.x * 256) >> 6;

    for (int i0 = wid * 2; i0 < E; i0 += nw * 2) {
        int eA = elist[i0];
        bool hasB = (i0 + 1 < E);
        int eB = hasB ? elist[i0 + 1] : eA;

        const float4* embA = (const float4*)(edge_emb + (size_t)eA * 16);
        const float4* embB = (const float4*)(edge_emb + (size_t)eB * 16);
        float4 a0 = embA[0], a1 = embA[1], a2 = embA[2], a3 = embA[3];
        float4 b0 = embB[0], b1 = embB[1], b2 = embB[2], b3 = embB[3];
        float xA = a0.x * wr1[0];
        xA = fmaf(a0.y, wr1[1], xA);  xA = fmaf(a0.z, wr1[2], xA);  xA = fmaf(a0.w, wr1[3], xA);
        xA = fmaf(a1.x, wr1[4], xA);  xA = fmaf(a1.y, wr1[5], xA);  xA = fmaf(a1.z, wr1[6], xA);
        xA = fmaf(a1.w, wr1[7], xA);  xA = fmaf(a2.x, wr1[8], xA);  xA = fmaf(a2.y, wr1[9], xA);
        xA = fmaf(a2.z, wr1[10], xA); xA = fmaf(a2.w, wr1[11], xA); xA = fmaf(a3.x, wr1[12], xA);
        xA = fmaf(a3.y, wr1[13], xA); xA = fmaf(a3.z, wr1[14], xA); xA = fmaf(a3.w, wr1[15], xA);
        float xB = b0.x * wr1[0];
        xB = fmaf(b0.y, wr1[1], xB);  xB = fmaf(b0.z, wr1[2], xB);  xB = fmaf(b0.w, wr1[3], xB);
        xB = fmaf(b1.x, wr1[4], xB);  xB = fmaf(b1.y, wr1[5], xB);  xB = fmaf(b1.z, wr1[6], xB);
        xB = fmaf(b1.w, wr1[7], xB);  xB = fmaf(b2.x, wr1[8], xB);  xB = fmaf(b2.y, wr1[9], xB);
        xB = fmaf(b2.z, wr1[10], xB); xB = fmaf(b2.w, wr1[11], xB); xB = fmaf(b3.x, wr1[12], xB);
        xB = fmaf(b3.y, wr1[13], xB); xB = fmaf(b3.z, wr1[14], xB); xB = fmaf(b3.w, wr1[15], xB);
        float hA = sspf(xA);
        float hB = sspf(xB);

        float waA = 0.f, wbA = 0.f, waB = 0.f, wbB = 0.f;
        #pragma unroll
        for (int q = 0; q < 32; ++q) {
            float4 ww = w2q[q * 64 + lane];
            float hA0 = rlane(hA, 2 * q), hA1 = rlane(hA, 2 * q + 1);
            float hB0 = rlane(hB, 2 * q), hB1 = rlane(hB, 2 * q + 1);
            waA = fmaf(hA0, ww.x, waA); wbA = fmaf(hA0, ww.y, wbA);
            waA = fmaf(hA1, ww.z, waA); wbA = fmaf(hA1, ww.w, wbA);
            waB = fmaf(hB0, ww.x, waB); wbB = fmaf(hB0, ww.y, wbB);
            waB = fmaf(hB1, ww.z, waB); wbB = fmaf(hB1, ww.w, wbB);
        }

        wstore(&w_s[(size_t)i0 * 128 + lane], waA);
        wstore(&w_s[(size_t)i0 * 128 + 64 + lane], wbA);
        if (hasB) {
            wstore(&w_s[(size_t)(i0 + 1) * 128 + lane], waB);
            wstore(&w_s[(size_t)(i0 + 1) * 128 + 64 + lane], wbB);
        }
    }
}

// ---------------- Kernel B2: per-node TP accumulation (sequential w reads) ----------------
// Wave per node. Lane j<32: w1/w2 channel j; lane 32+u: w4/w3 channel u.
template <typename WT>
__global__ __launch_bounds__(256) void k_agg2(
    const WT* __restrict__ w_s, const float4* __restrict__ pk,
    const int* __restrict__ srcs,
    const float* __restrict__ s_ws, const float* __restrict__ v_ws,
    const int* __restrict__ row_off,
    float* __restrict__ agg_s, float* __restrict__ agg_v, int N)
{
    int lane = threadIdx.x & 63;
    int n = blockIdx.x * 4 + (threadIdx.x >> 6);
    if (n >= N) return;
    int row = row_off[n], end = row_off[n + 1];
    int u = lane & 31;
    bool low = (lane < 32);
    float accs = 0.f, acc0 = 0.f, acc1 = 0.f, acc2 = 0.f;

    #pragma unroll 2
    for (int i = row; i < end; ++i) {
        float la = wload(&w_s[(size_t)i * 128 + lane]);        // low: w1[j], high: w2[u]
        float lb = wload(&w_s[(size_t)i * 128 + 64 + lane]);   // low: w3[j], high: w4[u]
        float4 m = pk[i];                                      // {y1x,y1y,y1z,y0}
        int src = srcs[i];
        const float* sp = s_ws + (size_t)src * 32;
        const float* vp = v_ws + (size_t)src * 96;
        float se = sp[u];
        float vx = vp[u], vy = vp[32 + u], vz = vp[64 + u];
        float xa = __shfl_xor(la, 32, 64);                     // low gets w2[j]
        float xb = __shfl_xor(lb, 32, 64);                     // high gets w3[u]
        float dot = vx * m.x + vy * m.y + vz * m.z;
        accs += low ? (la * se * m.w) : (lb * dot * INV_SQRT3);
        if (low) {
            float t = xa * se;
            acc0 = fmaf(t, m.x, acc0); acc1 = fmaf(t, m.y, acc1); acc2 = fmaf(t, m.z, acc2);
        } else {
            float t = xb * m.w;
            acc0 = fmaf(t, vx, acc0); acc1 = fmaf(t, vy, acc1); acc2 = fmaf(t, vz, acc2);
        }
    }

    agg_s[(size_t)n * 64 + lane] = accs;
    agg_v[(size_t)n * 192 + lane] = acc0;
    agg_v[(size_t)n * 192 + 64 + lane] = acc1;
    agg_v[(size_t)n * 192 + 128 + lane] = acc2;
}

// ---------------- Kernel C: linear_2 + self-connection + output ----------------
__global__ __launch_bounds__(256) void k_out(
    const float* __restrict__ node_s, const float* __restrict__ node_v,
    const float* __restrict__ attrs,
    const float* __restrict__ agg_s, const float* __restrict__ agg_v,
    const float* __restrict__ W2s, const float* __restrict__ W2v,
    const float* __restrict__ Wscs, const float* __restrict__ Wscv,
    float* __restrict__ out, int N)
{
    __shared__ float sW2s[2048], sW2v[2048], sCs[8192], sCv[8192];
    for (int i = threadIdx.x; i < 2048; i += 256) {
        sW2s[i] = W2s[i] * INV_2M_DEG;
        sW2v[i] = W2v[i] * INV_2M_DEG;
    }
    for (int i = threadIdx.x; i < 8192; i += 256) {
        sCs[i] = Wscs[i] * INV_FAN;
        sCv[i] = Wscv[i] * INV_FAN;
    }
    __syncthreads();
    int j = threadIdx.x & 31;
    int n = blockIdx.x * 8 + (threadIdx.x >> 5);
    if (n >= N) return;

    float at[8];
    #pragma unroll
    for (int a = 0; a < 8; ++a) at[a] = attrs[(size_t)n * 8 + a];

    float os = 0.f, o0 = 0.f, o1 = 0.f, o2 = 0.f;
    const float* ags = agg_s + (size_t)n * 64;
    const float* agv = agg_v + (size_t)n * 192;
    #pragma unroll
    for (int u = 0; u < 64; ++u) {
        float w2s = sW2s[u * 32 + j];
        float w2v = sW2v[u * 32 + j];
        os = fmaf(ags[u], w2s, os);
        o0 = fmaf(agv[u], w2v, o0);
        o1 = fmaf(agv[64 + u], w2v, o1);
        o2 = fmaf(agv[128 + u], w2v, o2);
    }

    const float* sn = node_s + (size_t)n * 32;
    const float* vn = node_v + (size_t)n * 96;
    #pragma unroll 4
    for (int u = 0; u < 32; ++u) {
        float su = sn[u];
        float v0 = vn[u * 3], v1 = vn[u * 3 + 1], v2 = vn[u * 3 + 2];
        #pragma unroll
        for (int a = 0; a < 8; ++a) {
            float ca = at[a];
            float wcs = sCs[(u * 8 + a) * 32 + j];
            float wcv = sCv[(u * 8 + a) * 32 + j];
            os = fmaf(su * ca, wcs, os);
            float t = ca * wcv;
            o0 = fmaf(v0, t, o0);
            o1 = fmaf(v1, t, o1);
            o2 = fmaf(v2, t, o2);
        }
    }

    float* op = out + (size_t)n * 128;
    op[j] = os;
    op[32 + j * 3 + 0] = o0;
    op[32 + j * 3 + 1] = o1;
    op[32 + j * 3 + 2] = o2;
}

extern "C" void kernel_launch(void* const* d_in, const int* in_sizes, int n_in,
                              void* d_out, int out_size, void* d_ws, size_t ws_size,
                              hipStream_t stream)
{
    const float* node_s = (const float*)d_in[0];
    const float* node_v = (const float*)d_in[1];
    const float* attrs  = (const float*)d_in[2];
    const float* emb    = (const float*)d_in[3];
    const float* y0     = (const float*)d_in[4];
    const float* y1     = (const float*)d_in[5];
    const int*   eidx   = (const int*)d_in[6];
    const float* W1s  = (const float*)d_in[7];
    const float* W1v  = (const float*)d_in[8];
    const float* Wr1  = (const float*)d_in[9];
    const float* Wr2  = (const float*)d_in[10];
    const float* W2s  = (const float*)d_in[11];
    const float* W2v  = (const float*)d_in[12];
    const float* Wscs = (const float*)d_in[13];
    const float* Wscv = (const float*)d_in[14];

    int N = in_sizes[0] / 32;   // 20000
    int E = in_sizes[3] / 16;   // 640000

    float* s_ws  = (float*)d_ws;                    // N*32
    float* v_ws  = s_ws + (size_t)N * 32;           // N*96
    float* agg_s = v_ws + (size_t)N * 96;           // N*64
    float* agg_v = agg_s + (size_t)N * 64;          // N*192
    float4* pk   = (float4*)(agg_v + (size_t)N * 192); // E float4s
    char*  wreg  = (char*)(pk + (size_t)E);

    size_t fixed    = (size_t)N * 384 * 4 + (size_t)E * 16;
    size_t intbytes = ((size_t)N * 3 + 1 + (size_t)E * 2) * 4;
    size_t w_f32    = (size_t)E * 128 * 4;
    size_t w_bf16   = (size_t)E * 128 * 2;
    bool use_f32 = (ws_size >= fixed + w_f32 + intbytes);

    char* ip = wreg + (use_f32 ? w_f32 : w_bf16);
    int* count   = (int*)ip;          // N
    int* row_off = count + N;         // N+1
    int* cursor  = row_off + (N + 1); // N
    int* elist   = cursor + N;        // E
    int* srcs    = elist + E;         // E

    hipMemsetAsync(count, 0, (size_t)N * sizeof(int), stream);

    k_lin1<<<dim3((N + 7) / 8), dim3(256), 0, stream>>>(node_s, node_v, W1s, W1v, s_ws, v_ws, N);
    k_hist<<<dim3((E + 255) / 256), dim3(256), 0, stream>>>(eidx, count, E);
    k_scan<<<dim3(1), dim3(1024), 0, stream>>>(count, row_off, cursor, N);
    k_fill<<<dim3((E + 255) / 256), dim3(256), 0, stream>>>(eidx, y0, y1, cursor, elist, pk, srcs, E);

    if (use_f32) {
        k_mlp<float><<<dim3(2048), dim3(256), 0, stream>>>(emb, elist, Wr1, Wr2, (float*)wreg, E);
        k_agg2<float><<<dim3((N + 3) / 4), dim3(256), 0, stream>>>((const float*)wreg, pk, srcs,
                                                                   s_ws, v_ws, row_off, agg_s, agg_v, N);
    } else {
        k_mlp<__hip_bfloat16><<<dim3(2048), dim3(256), 0, stream>>>(emb, elist, Wr1, Wr2,
                                                                    (__hip_bfloat16*)wreg, E);
        k_agg2<__hip_bfloat16><<<dim3((N + 3) / 4), dim3(256), 0, stream>>>(
            (const __hip_bfloat16*)wreg, pk, srcs, s_ws, v_ws, row_off, agg_s, agg_v, N);
    }

    k_out<<<dim3((N + 7) / 8), dim3(256), 0, stream>>>(node_s, node_v, attrs, agg_s, agg_v,
                                                       W2s, W2v, Wscs, Wscv, (float*)d_out, N);
}

// Round 4
// 506.229 us; speedup vs baseline: 1.7427x; 1.4327x over previous
//
#include <hip/hip_runtime.h>
#include <math.h>

typedef short bf16x8 __attribute__((ext_vector_type(8)));
typedef short short4v __attribute__((ext_vector_type(4)));
typedef float f32x4 __attribute__((ext_vector_type(4)));

__device__ __forceinline__ float sspf(float x) {
    return __logf(1.0f + __expf(x)) - 0.6931471805599453f;
}
// fp32 -> bf16 (RNE)
__device__ __forceinline__ short f2b(float f) {
    union { float f; unsigned u; } c; c.f = f;
    unsigned r = c.u + 0x7fff + ((c.u >> 16) & 1);
    return (short)(r >> 16);
}
__device__ __forceinline__ float b2f(short s) {
    union { unsigned u; float f; } c; c.u = ((unsigned)(unsigned short)s) << 16;
    return c.f;
}

constexpr float INV_M      = 0.17677669529663687f;   // 1/sqrt(32)
constexpr float INV_R      = 0.25f;                  // 1/sqrt(16)
constexpr float INV_H      = 0.125f;                 // 1/sqrt(64)
constexpr float INV_2M_DEG = 0.125f * 0.17677669529663687f; // 1/sqrt(64)*1/sqrt(32)
constexpr float INV_FAN    = 0.0625f;                // 1/sqrt(32*8)
constexpr float INV_SQRT3  = 0.5773502691896258f;

// ---------------- Kernel A: linear_1 ----------------
__global__ __launch_bounds__(256) void k_lin1(
    const float* __restrict__ node_s, const float* __restrict__ node_v,
    const float* __restrict__ W1s, const float* __restrict__ W1v,
    float* __restrict__ s_ws, float* __restrict__ v_ws, int N)
{
    __shared__ float sWs[1024], sWv[1024];
    for (int i = threadIdx.x; i < 1024; i += 256) {
        sWs[i] = W1s[i] * INV_M;
        sWv[i] = W1v[i] * INV_M;
    }
    __syncthreads();
    int j = threadIdx.x & 31;
    int n = blockIdx.x * 8 + (threadIdx.x >> 5);
    if (n >= N) return;
    const float* ss = node_s + (size_t)n * 32;
    const float* vv = node_v + (size_t)n * 96;
    float as = 0.f, a0 = 0.f, a1 = 0.f, a2 = 0.f;
    #pragma unroll
    for (int u = 0; u < 32; ++u) {
        float ws_ = sWs[u * 32 + j];
        float wv_ = sWv[u * 32 + j];
        as = fmaf(ss[u], ws_, as);
        a0 = fmaf(vv[u * 3 + 0], wv_, a0);
        a1 = fmaf(vv[u * 3 + 1], wv_, a1);
        a2 = fmaf(vv[u * 3 + 2], wv_, a2);
    }
    s_ws[(size_t)n * 32 + j] = as;
    v_ws[(size_t)n * 96 + j] = a0;
    v_ws[(size_t)n * 96 + 32 + j] = a1;
    v_ws[(size_t)n * 96 + 64 + j] = a2;
}

// ---------------- CSR build ----------------
__global__ __launch_bounds__(256) void k_hist(
    const int* __restrict__ eidx, int* __restrict__ count, int E)
{
    int e = blockIdx.x * 256 + threadIdx.x;
    if (e < E) atomicAdd(&count[eidx[E + e]], 1);
}

__global__ __launch_bounds__(1024) void k_scan(
    const int* __restrict__ count, int* __restrict__ row_off,
    int* __restrict__ cursor, int N)
{
    __shared__ int wsum[16], woff[16];
    int tid = threadIdx.x;
    int per = (N + 1023) / 1024;
    int base = tid * per;
    int lim = min(N, base + per);
    int s = 0;
    for (int i = base; i < lim; ++i) s += count[i];
    int lane = tid & 63, wv = tid >> 6;
    int x = s;
    #pragma unroll
    for (int off = 1; off < 64; off <<= 1) {
        int y = __shfl_up(x, off, 64);
        if (lane >= off) x += y;
    }
    if (lane == 63) wsum[wv] = x;
    __syncthreads();
    if (wv == 0 && lane < 16) {
        int t = wsum[lane];
        int xx = t;
        #pragma unroll
        for (int off = 1; off < 16; off <<= 1) {
            int y = __shfl_up(xx, off, 64);
            if (lane >= off) xx += y;
        }
        woff[lane] = xx - t;
        if (lane == 15) row_off[N] = xx;
    }
    __syncthreads();
    int run = x - s + woff[wv];
    for (int i = base; i < lim; ++i) {
        int c = count[i];
        row_off[i] = run;
        cursor[i] = run;
        run += c;
    }
}

// CSR fill: per-slot edge id, packed {y1,y0}, src node, dst node
__global__ __launch_bounds__(256) void k_fill(
    const int* __restrict__ eidx, const float* __restrict__ y0,
    const float* __restrict__ y1, int* __restrict__ cursor,
    int* __restrict__ elist, float4* __restrict__ pk,
    int* __restrict__ srcs, int* __restrict__ dsts, int E)
{
    int e = blockIdx.x * 256 + threadIdx.x;
    if (e < E) {
        int d = eidx[E + e];
        int slot = atomicAdd(&cursor[d], 1);
        elist[slot] = e;
        srcs[slot] = eidx[e];
        dsts[slot] = d;
        pk[slot] = make_float4(y1[(size_t)e * 3], y1[(size_t)e * 3 + 1],
                               y1[(size_t)e * 3 + 2], y0[e]);
    }
}

// ---------------- Fused: MFMA radial MLP + CG TP + segmented accumulate ----------------
// Block = 4 waves; wave owns 64 consecutive CSR slots, processed as 4 chunks of 16.
// Per chunk: layer1 MFMA (K=16 padded to 32), ssp, layer2 MFMA vs LDS Wr2 frags,
// w tile -> per-wave LDS (bf16, transposed [c][m]); then TP with flush-on-dst-change.
__global__ __launch_bounds__(256) void k_fused(
    const float* __restrict__ emb, const int* __restrict__ elist,
    const int* __restrict__ srcs, const int* __restrict__ dsts,
    const float4* __restrict__ pk,
    const float* __restrict__ Wr1, const float* __restrict__ Wr2,
    const float* __restrict__ s_ws, const float* __restrict__ v_ws,
    float* __restrict__ agg_s, float* __restrict__ agg_v, int E)
{
    __shared__ short sB2[16 * 512];       // 16 Wr2 fragments (nt,kc), frag-order, 16 KB
    __shared__ short hbuf[4][16 * 72];    // per-wave h tile [m][k], stride 72 bf16
    __shared__ short wbuf[4][128 * 20];   // per-wave w tile [c][m], stride 20 bf16

    int tid = threadIdx.x;
    for (int i = tid; i < 1024; i += 256) {
        int f = i >> 6, ln = i & 63;
        int nt = f >> 1, kc = f & 1;
        int qq = ln >> 4, n = nt * 16 + (ln & 15);
        short* d8 = &sB2[f * 512 + ln * 8];
        #pragma unroll
        for (int j = 0; j < 8; ++j) {
            int k = kc * 32 + qq * 8 + j;
            d8[j] = f2b(Wr2[k * 128 + n] * INV_H);
        }
    }
    __syncthreads();

    int lane = tid & 63;
    int wv = tid >> 6;
    int q = lane >> 4, lm = lane & 15;
    int u = lane & 31;
    bool low = (lane < 32);

    // layer-1 B fragments (Wr1, K padded 16->32 with zeros) in VGPRs
    bf16x8 wr1f[4];
    #pragma unroll
    for (int nt = 0; nt < 4; ++nt) {
        #pragma unroll
        for (int j = 0; j < 8; ++j) {
            int k = q * 8 + j;
            wr1f[nt][j] = (k < 16) ? f2b(Wr1[k * 64 + nt * 16 + lm] * INV_R) : (short)0;
        }
    }

    short* hl = hbuf[wv];
    short* wl = wbuf[wv];

    int base = blockIdx.x * 256 + wv * 64;
    float accs = 0.f, acc0 = 0.f, acc1 = 0.f, acc2 = 0.f;
    int cur = -1;

    for (int ch = 0; ch < 4; ++ch) {
        int cb = base + ch * 16;
        if (cb >= E) break;

        // ---- layer 1: A = emb[slots], one MFMA per n-tile ----
        int s_m = min(cb + lm, E - 1);
        int e_m = elist[s_m];
        bf16x8 af;
        if (q < 2) {
            const float* ep = emb + (size_t)e_m * 16 + q * 8;
            float4 pA = *(const float4*)ep;
            float4 pB = *(const float4*)(ep + 4);
            af[0] = f2b(pA.x); af[1] = f2b(pA.y); af[2] = f2b(pA.z); af[3] = f2b(pA.w);
            af[4] = f2b(pB.x); af[5] = f2b(pB.y); af[6] = f2b(pB.z); af[7] = f2b(pB.w);
        } else {
            af = (bf16x8){0, 0, 0, 0, 0, 0, 0, 0};
        }
        #pragma unroll
        for (int nt = 0; nt < 4; ++nt) {
            f32x4 x = __builtin_amdgcn_mfma_f32_16x16x32_bf16(
                af, wr1f[nt], (f32x4){0.f, 0.f, 0.f, 0.f}, 0, 0, 0);
            int c = nt * 16 + lm;
            #pragma unroll
            for (int r = 0; r < 4; ++r)
                hl[(q * 4 + r) * 72 + c] = f2b(sspf(x[r]));
        }

        // ---- layer 2: 16 MFMA, D -> w tile (transposed, bf16) ----
        bf16x8 ha = *(const bf16x8*)&hl[lm * 72 + q * 8];        // kc=0
        bf16x8 hb = *(const bf16x8*)&hl[lm * 72 + 32 + q * 8];   // kc=1
        #pragma unroll
        for (int nt = 0; nt < 8; ++nt) {
            bf16x8 b0 = *(const bf16x8*)&sB2[(nt * 2 + 0) * 512 + lane * 8];
            bf16x8 b1 = *(const bf16x8*)&sB2[(nt * 2 + 1) * 512 + lane * 8];
            f32x4 acc = __builtin_amdgcn_mfma_f32_16x16x32_bf16(
                ha, b0, (f32x4){0.f, 0.f, 0.f, 0.f}, 0, 0, 0);
            acc = __builtin_amdgcn_mfma_f32_16x16x32_bf16(hb, b1, acc, 0, 0, 0);
            int c = nt * 16 + lm;
            short4v pkd = {f2b(acc[0]), f2b(acc[1]), f2b(acc[2]), f2b(acc[3])};
            *(short4v*)&wl[c * 20 + q * 4] = pkd;
        }

        // ---- per-slot metadata broadcast: lanes 0-15 dsts, 16-31 srcs ----
        int midx = min(cb + (lane & 15), E - 1);
        int meta = (lane < 16) ? dsts[midx] : (lane < 32 ? srcs[midx] : 0);

        // ---- TP + segmented accumulation ----
        #pragma unroll 4
        for (int i = 0; i < 16; ++i) {
            int s = cb + i;
            if (s >= E) break;
            int d = __shfl(meta, i, 64);
            if (d != cur) {
                if (cur >= 0) {
                    atomicAdd(&agg_s[(size_t)cur * 64 + lane], accs);
                    float* av = &agg_v[(size_t)cur * 192 + lane];
                    atomicAdd(av, acc0); atomicAdd(av + 64, acc1); atomicAdd(av + 128, acc2);
                }
                accs = acc0 = acc1 = acc2 = 0.f;
                cur = d;
            }
            float la = b2f(wl[lane * 20 + i]);          // low: w1[j]   high: w2[u]
            float lb = b2f(wl[(64 + lane) * 20 + i]);   // low: w3[j]   high: w4[u]
            float4 m4 = pk[s];
            int src = __shfl(meta, 16 + i, 64);
            const float* sp = s_ws + (size_t)src * 32;
            const float* vp = v_ws + (size_t)src * 96;
            float se = sp[u];
            float vx = vp[u], vy = vp[32 + u], vz = vp[64 + u];
            float xa = __shfl_xor(la, 32, 64);          // low gets w2[j]
            float xb = __shfl_xor(lb, 32, 64);          // high gets w3[u]
            float dot = vx * m4.x + vy * m4.y + vz * m4.z;
            accs += low ? (la * se * m4.w) : (lb * dot * INV_SQRT3);
            if (low) {
                float t = xa * se;
                acc0 = fmaf(t, m4.x, acc0); acc1 = fmaf(t, m4.y, acc1); acc2 = fmaf(t, m4.z, acc2);
            } else {
                float t = xb * m4.w;
                acc0 = fmaf(t, vx, acc0); acc1 = fmaf(t, vy, acc1); acc2 = fmaf(t, vz, acc2);
            }
        }
    }
    if (cur >= 0) {
        atomicAdd(&agg_s[(size_t)cur * 64 + lane], accs);
        float* av = &agg_v[(size_t)cur * 192 + lane];
        atomicAdd(av, acc0); atomicAdd(av + 64, acc1); atomicAdd(av + 128, acc2);
    }
}

// ---------------- Kernel C: linear_2 + self-connection + output ----------------
__global__ __launch_bounds__(256) void k_out(
    const float* __restrict__ node_s, const float* __restrict__ node_v,
    const float* __restrict__ attrs,
    const float* __restrict__ agg_s, const float* __restrict__ agg_v,
    const float* __restrict__ W2s, const float* __restrict__ W2v,
    const float* __restrict__ Wscs, const float* __restrict__ Wscv,
    float* __restrict__ out, int N)
{
    __shared__ float sW2s[2048], sW2v[2048], sCs[8192], sCv[8192];
    for (int i = threadIdx.x; i < 2048; i += 256) {
        sW2s[i] = W2s[i] * INV_2M_DEG;
        sW2v[i] = W2v[i] * INV_2M_DEG;
    }
    for (int i = threadIdx.x; i < 8192; i += 256) {
        sCs[i] = Wscs[i] * INV_FAN;
        sCv[i] = Wscv[i] * INV_FAN;
    }
    __syncthreads();
    int j = threadIdx.x & 31;
    int n = blockIdx.x * 8 + (threadIdx.x >> 5);
    if (n >= N) return;

    float at[8];
    #pragma unroll
    for (int a = 0; a < 8; ++a) at[a] = attrs[(size_t)n * 8 + a];

    float os = 0.f, o0 = 0.f, o1 = 0.f, o2 = 0.f;
    const float* ags = agg_s + (size_t)n * 64;
    const float* agv = agg_v + (size_t)n * 192;
    #pragma unroll
    for (int u = 0; u < 64; ++u) {
        float w2s = sW2s[u * 32 + j];
        float w2v = sW2v[u * 32 + j];
        os = fmaf(ags[u], w2s, os);
        o0 = fmaf(agv[u], w2v, o0);
        o1 = fmaf(agv[64 + u], w2v, o1);
        o2 = fmaf(agv[128 + u], w2v, o2);
    }

    const float* sn = node_s + (size_t)n * 32;
    const float* vn = node_v + (size_t)n * 96;
    #pragma unroll 4
    for (int u = 0; u < 32; ++u) {
        float su = sn[u];
        float v0 = vn[u * 3], v1 = vn[u * 3 + 1], v2 = vn[u * 3 + 2];
        #pragma unroll
        for (int a = 0; a < 8; ++a) {
            float ca = at[a];
            float wcs = sCs[(u * 8 + a) * 32 + j];
            float wcv = sCv[(u * 8 + a) * 32 + j];
            os = fmaf(su * ca, wcs, os);
            float t = ca * wcv;
            o0 = fmaf(v0, t, o0);
            o1 = fmaf(v1, t, o1);
            o2 = fmaf(v2, t, o2);
        }
    }

    float* op = out + (size_t)n * 128;
    op[j] = os;
    op[32 + j * 3 + 0] = o0;
    op[32 + j * 3 + 1] = o1;
    op[32 + j * 3 + 2] = o2;
}

extern "C" void kernel_launch(void* const* d_in, const int* in_sizes, int n_in,
                              void* d_out, int out_size, void* d_ws, size_t ws_size,
                              hipStream_t stream)
{
    const float* node_s = (const float*)d_in[0];
    const float* node_v = (const float*)d_in[1];
    const float* attrs  = (const float*)d_in[2];
    const float* emb    = (const float*)d_in[3];
    const float* y0     = (const float*)d_in[4];
    const float* y1     = (const float*)d_in[5];
    const int*   eidx   = (const int*)d_in[6];
    const float* W1s  = (const float*)d_in[7];
    const float* W1v  = (const float*)d_in[8];
    const float* Wr1  = (const float*)d_in[9];
    const float* Wr2  = (const float*)d_in[10];
    const float* W2s  = (const float*)d_in[11];
    const float* W2v  = (const float*)d_in[12];
    const float* Wscs = (const float*)d_in[13];
    const float* Wscv = (const float*)d_in[14];

    int N = in_sizes[0] / 32;   // 20000
    int E = in_sizes[3] / 16;   // 640000

    float* s_ws  = (float*)d_ws;                       // N*32
    float* v_ws  = s_ws + (size_t)N * 32;              // N*96
    float* agg_s = v_ws + (size_t)N * 96;              // N*64
    float* agg_v = agg_s + (size_t)N * 64;             // N*192
    float4* pk   = (float4*)(agg_v + (size_t)N * 192); // E float4
    int* count   = (int*)(pk + (size_t)E);             // N
    int* row_off = count + N;                          // N+1
    int* cursor  = row_off + (N + 1);                  // N
    int* elist   = cursor + N;                         // E
    int* srcs    = elist + E;                          // E
    int* dsts    = srcs + E;                           // E

    hipMemsetAsync(count, 0, (size_t)N * sizeof(int), stream);
    hipMemsetAsync(agg_s, 0, (size_t)N * 256 * sizeof(float), stream);

    k_lin1<<<dim3((N + 7) / 8), dim3(256), 0, stream>>>(node_s, node_v, W1s, W1v, s_ws, v_ws, N);
    k_hist<<<dim3((E + 255) / 256), dim3(256), 0, stream>>>(eidx, count, E);
    k_scan<<<dim3(1), dim3(1024), 0, stream>>>(count, row_off, cursor, N);
    k_fill<<<dim3((E + 255) / 256), dim3(256), 0, stream>>>(eidx, y0, y1, cursor,
                                                            elist, pk, srcs, dsts, E);
    k_fused<<<dim3((E + 255) / 256), dim3(256), 0, stream>>>(emb, elist, srcs, dsts, pk,
                                                             Wr1, Wr2, s_ws, v_ws,
                                                             agg_s, agg_v, E);
    k_out<<<dim3((N + 7) / 8), dim3(256), 0, stream>>>(node_s, node_v, attrs, agg_s, agg_v,
                                                       W2s, W2v, Wscs, Wscv, (float*)d_out, N);
}

// Round 6
// 430.665 us; speedup vs baseline: 2.0485x; 1.1755x over previous
//
#include <hip/hip_runtime.h>
#include <math.h>

typedef short bf16x8 __attribute__((ext_vector_type(8)));
typedef short short2v __attribute__((ext_vector_type(2)));
typedef float f32x4 __attribute__((ext_vector_type(4)));

__device__ __forceinline__ float sspf(float x) {
    return __logf(1.0f + __expf(x)) - 0.6931471805599453f;
}
__device__ __forceinline__ short f2b(float f) {
    union { float f; unsigned u; } c; c.f = f;
    unsigned r = c.u + 0x7fff + ((c.u >> 16) & 1);
    return (short)(r >> 16);
}
__device__ __forceinline__ float b2f(short s) {
    union { unsigned u; float f; } c; c.u = ((unsigned)(unsigned short)s) << 16;
    return c.f;
}
__device__ __forceinline__ int rlanei(int v, int l) {
    return __builtin_amdgcn_readlane(v, l);
}
__device__ __forceinline__ float rlanef(float v, int l) {
    return __uint_as_float(__builtin_amdgcn_readlane(__float_as_uint(v), l));
}

constexpr float INV_M      = 0.17677669529663687f;   // 1/sqrt(32)
constexpr float INV_R      = 0.25f;                  // 1/sqrt(16)
constexpr float INV_H      = 0.125f;                 // 1/sqrt(64)
constexpr float INV_2M_DEG = 0.125f * 0.17677669529663687f; // 1/sqrt(64)*1/sqrt(32)
constexpr float INV_FAN    = 0.0625f;                // 1/sqrt(32*8)
constexpr float INV_SQRT3  = 0.5773502691896258f;

// ---------------- Kernel A: linear_1 + (fused) edge histogram ----------------
__global__ __launch_bounds__(256) void k_lin1h(
    const float* __restrict__ node_s, const float* __restrict__ node_v,
    const float* __restrict__ W1s, const float* __restrict__ W1v,
    float* __restrict__ s_ws, float* __restrict__ v_ws, int N,
    const int* __restrict__ eidx, int* __restrict__ count, int E, int nblin)
{
    if ((int)blockIdx.x >= nblin) {
        int e = (blockIdx.x - nblin) * 256 + threadIdx.x;
        if (e < E) atomicAdd(&count[eidx[E + e]], 1);
        return;
    }
    __shared__ float sWs[1024], sWv[1024];
    for (int i = threadIdx.x; i < 1024; i += 256) {
        sWs[i] = W1s[i] * INV_M;
        sWv[i] = W1v[i] * INV_M;
    }
    __syncthreads();
    int j = threadIdx.x & 31;
    int n = blockIdx.x * 8 + (threadIdx.x >> 5);
    if (n >= N) return;
    const float* ss = node_s + (size_t)n * 32;
    const float* vv = node_v + (size_t)n * 96;
    float as = 0.f, a0 = 0.f, a1 = 0.f, a2 = 0.f;
    #pragma unroll
    for (int u = 0; u < 32; ++u) {
        float ws_ = sWs[u * 32 + j];
        float wv_ = sWv[u * 32 + j];
        as = fmaf(ss[u], ws_, as);
        a0 = fmaf(vv[u * 3 + 0], wv_, a0);
        a1 = fmaf(vv[u * 3 + 1], wv_, a1);
        a2 = fmaf(vv[u * 3 + 2], wv_, a2);
    }
    s_ws[(size_t)n * 32 + j] = as;
    v_ws[(size_t)n * 96 + j] = a0;
    v_ws[(size_t)n * 96 + 32 + j] = a1;
    v_ws[(size_t)n * 96 + 64 + j] = a2;
}

__global__ __launch_bounds__(1024) void k_scan(
    const int* __restrict__ count, int* __restrict__ row_off,
    int* __restrict__ cursor, int N)
{
    __shared__ int wsum[16], woff[16];
    int tid = threadIdx.x;
    int per = (N + 1023) / 1024;
    int base = tid * per;
    int lim = min(N, base + per);
    int s = 0;
    for (int i = base; i < lim; ++i) s += count[i];
    int lane = tid & 63, wv = tid >> 6;
    int x = s;
    #pragma unroll
    for (int off = 1; off < 64; off <<= 1) {
        int y = __shfl_up(x, off, 64);
        if (lane >= off) x += y;
    }
    if (lane == 63) wsum[wv] = x;
    __syncthreads();
    if (wv == 0 && lane < 16) {
        int t = wsum[lane];
        int xx = t;
        #pragma unroll
        for (int off = 1; off < 16; off <<= 1) {
            int y = __shfl_up(xx, off, 64);
            if (lane >= off) xx += y;
        }
        woff[lane] = xx - t;
        if (lane == 15) row_off[N] = xx;
    }
    __syncthreads();
    int run = x - s + woff[wv];
    for (int i = base; i < lim; ++i) {
        int c = count[i];
        row_off[i] = run;
        cursor[i] = run;
        run += c;
    }
}

__global__ __launch_bounds__(256) void k_fill(
    const int* __restrict__ eidx, const float* __restrict__ y0,
    const float* __restrict__ y1, int* __restrict__ cursor,
    int* __restrict__ elist, float4* __restrict__ pk,
    int* __restrict__ srcs, int* __restrict__ dsts, int E)
{
    int e = blockIdx.x * 256 + threadIdx.x;
    if (e < E) {
        int d = eidx[E + e];
        int slot = atomicAdd(&cursor[d], 1);
        elist[slot] = e;
        srcs[slot] = eidx[e];
        dsts[slot] = d;
        pk[slot] = make_float4(y1[(size_t)e * 3], y1[(size_t)e * 3 + 1],
                               y1[(size_t)e * 3 + 2], y0[e]);
    }
}

// ---------------- Fused: MFMA radial MLP + CG TP + segmented accumulate ----------------
// Block = 4 waves; wave owns 64 consecutive CSR slots, 4 chunks of 16.
// w tile stored permuted [A|B][c'][m] (stride 18 halves) so the TP needs no shuffles:
//   A[c'] : c'<32 -> w1[c'], c'=32+u -> w3[u]
//   B[c'] : c'<32 -> w2[c'], c'=32+u -> w4[u]
// NOTE: all wl/hl stores use short-element types (same TBAA class as the short reads);
// an unsigned-punned store here miscompiled (reads hoisted past writes) in round 5.
__global__ __launch_bounds__(256) void k_fused(
    const float* __restrict__ emb, const int* __restrict__ elist,
    const int* __restrict__ srcs, const int* __restrict__ dsts,
    const float4* __restrict__ pk,
    const float* __restrict__ Wr1, const float* __restrict__ Wr2,
    const float* __restrict__ s_ws, const float* __restrict__ v_ws,
    float* __restrict__ agg_s, float* __restrict__ agg_v, int E)
{
    __shared__ short sW1[4 * 512];          // layer1 B frags, shared across waves (4 KB)
    __shared__ short hbuf[4][16 * 72];      // per-wave h tile [m][hid], stride 72 halves
    __shared__ short wtl[4][2 * 64 * 18];   // per-wave w tiles [A|B][c'][m], stride 18 halves

    int tid = threadIdx.x;
    {   // stage Wr1 fragments (K padded 16->32 with zeros)
        int f = tid >> 6, ln = tid & 63;
        int qq = ln >> 4, lmm = ln & 15;
        short* d8 = &sW1[(f * 64 + ln) * 8];
        #pragma unroll
        for (int j = 0; j < 8; ++j) {
            int k = qq * 8 + j;
            d8[j] = (k < 16) ? f2b(Wr1[k * 64 + f * 16 + lmm] * INV_R) : (short)0;
        }
    }
    __syncthreads();

    int lane = tid & 63, wv = tid >> 6;
    int q = lane >> 4, lm = lane & 15;
    int u = lane & 31;
    bool low = (lane < 32);

    // Wr2 fragments in VGPRs (16 frags x 4 VGPR = 64 VGPRs)
    bf16x8 wr2f[16];
    #pragma unroll
    for (int nt = 0; nt < 8; ++nt) {
        #pragma unroll
        for (int kc = 0; kc < 2; ++kc) {
            #pragma unroll
            for (int j = 0; j < 8; ++j) {
                int k = kc * 32 + q * 8 + j;
                wr2f[nt * 2 + kc][j] = f2b(Wr2[k * 128 + nt * 16 + lm] * INV_H);
            }
        }
    }

    short* hl = hbuf[wv];
    short* wl = wtl[wv];

    int base = blockIdx.x * 256 + wv * 64;
    if (base >= E) return;   // E is a multiple of 256 here (640000)

    // preload chunk-0 emb
    int em = elist[min(base + lm, E - 1)];
    float4 pa = make_float4(0.f, 0.f, 0.f, 0.f);
    float4 pb = make_float4(0.f, 0.f, 0.f, 0.f);
    if (q < 2) {
        const float* ep = emb + (size_t)em * 16 + q * 8;
        pa = *(const float4*)ep;
        pb = *(const float4*)(ep + 4);
    }

    float accs = 0.f, acc0 = 0.f, acc1 = 0.f, acc2 = 0.f;
    int cur = -1;

    for (int ch = 0; ch < 4; ++ch) {
        int cb = base + ch * 16;

        // meta/pk loads for this chunk (issued early; used in TP)
        int meta = (lane < 16) ? dsts[cb + lm] : (lane < 32 ? srcs[cb + lm] : 0);
        float pkm = ((const float*)pk)[(size_t)(cb + lm) * 4 + q];  // slot=lm, comp=q

        // pack A fragment for layer 1
        bf16x8 af = (bf16x8){0, 0, 0, 0, 0, 0, 0, 0};
        if (q < 2) {
            af[0] = f2b(pa.x); af[1] = f2b(pa.y); af[2] = f2b(pa.z); af[3] = f2b(pa.w);
            af[4] = f2b(pb.x); af[5] = f2b(pb.y); af[6] = f2b(pb.z); af[7] = f2b(pb.w);
        }
        // prefetch next chunk's emb
        if (ch < 3) {
            em = elist[min(cb + 16 + lm, E - 1)];
            if (q < 2) {
                const float* ep = emb + (size_t)em * 16 + q * 8;
                pa = *(const float4*)ep;
                pb = *(const float4*)(ep + 4);
            }
        }

        // ---- layer 1: 4 MFMA -> hbuf ----
        #pragma unroll
        for (int nt = 0; nt < 4; ++nt) {
            bf16x8 bf = *(const bf16x8*)&sW1[(nt * 64 + lane) * 8];
            f32x4 x = __builtin_amdgcn_mfma_f32_16x16x32_bf16(
                af, bf, (f32x4){0.f, 0.f, 0.f, 0.f}, 0, 0, 0);
            #pragma unroll
            for (int r = 0; r < 4; ++r)
                hl[(q * 4 + r) * 72 + nt * 16 + lm] = f2b(sspf(x[r]));
        }

        // ---- layer 2: 16 MFMA -> permuted w tile ----
        bf16x8 ha = *(const bf16x8*)&hl[lm * 72 + q * 8];
        bf16x8 hb = *(const bf16x8*)&hl[lm * 72 + 32 + q * 8];
        #pragma unroll
        for (int nt = 0; nt < 8; ++nt) {
            f32x4 acc = __builtin_amdgcn_mfma_f32_16x16x32_bf16(
                ha, wr2f[nt * 2], (f32x4){0.f, 0.f, 0.f, 0.f}, 0, 0, 0);
            acc = __builtin_amdgcn_mfma_f32_16x16x32_bf16(hb, wr2f[nt * 2 + 1], acc, 0, 0, 0);
            int cp = (nt & 1) * 16 + lm + ((nt >> 2) & 1) * 32;   // c' row
            int half = (nt >> 1) & 1;                             // 0 = A, 1 = B
            short* wp = &wl[half * 1152 + cp * 18 + q * 4];
            short2v p01 = {f2b(acc[0]), f2b(acc[1])};
            short2v p23 = {f2b(acc[2]), f2b(acc[3])};
            *(short2v*)&wp[0] = p01;
            *(short2v*)&wp[2] = p23;
        }

        // ---- TP + segmented accumulation, 4-deep gather pipeline ----
        float pse[4], pvx[4], pvy[4], pvz[4];
        #pragma unroll
        for (int k = 0; k < 4; ++k) {
            int sr = rlanei(meta, 16 + k);
            const float* sp = s_ws + (size_t)sr * 32;
            const float* vp = v_ws + (size_t)sr * 96;
            pse[k] = sp[u]; pvx[k] = vp[u]; pvy[k] = vp[32 + u]; pvz[k] = vp[64 + u];
        }
        #pragma unroll
        for (int i = 0; i < 16; ++i) {
            float se = pse[i & 3], vx = pvx[i & 3], vy = pvy[i & 3], vz = pvz[i & 3];
            if (i + 4 < 16) {
                int sr = rlanei(meta, 16 + i + 4);
                const float* sp = s_ws + (size_t)sr * 32;
                const float* vp = v_ws + (size_t)sr * 96;
                pse[(i + 4) & 3] = sp[u]; pvx[(i + 4) & 3] = vp[u];
                pvy[(i + 4) & 3] = vp[32 + u]; pvz[(i + 4) & 3] = vp[64 + u];
            }
            int d = rlanei(meta, i);
            if (d != cur) {
                if (cur >= 0) {
                    atomicAdd(&agg_s[(size_t)cur * 64 + lane], accs);
                    float* av = &agg_v[(size_t)cur * 192 + lane];
                    atomicAdd(av, acc0); atomicAdd(av + 64, acc1); atomicAdd(av + 128, acc2);
                }
                accs = acc0 = acc1 = acc2 = 0.f;
                cur = d;
            }
            float la = b2f(wl[lane * 18 + i]);            // low: w1[j]  high: w3[u]
            float lb = b2f(wl[1152 + lane * 18 + i]);     // low: w2[j]  high: w4[u]
            float y1x = rlanef(pkm, i);
            float y1y = rlanef(pkm, 16 + i);
            float y1z = rlanef(pkm, 32 + i);
            float y0e = rlanef(pkm, 48 + i);
            float dot = vx * y1x + vy * y1y + vz * y1z;
            accs += low ? (la * se * y0e) : (lb * dot * INV_SQRT3);
            float t = low ? (lb * se) : (la * y0e);
            acc0 = fmaf(t, low ? y1x : vx, acc0);
            acc1 = fmaf(t, low ? y1y : vy, acc1);
            acc2 = fmaf(t, low ? y1z : vz, acc2);
        }
    }
    if (cur >= 0) {
        atomicAdd(&agg_s[(size_t)cur * 64 + lane], accs);
        float* av = &agg_v[(size_t)cur * 192 + lane];
        atomicAdd(av, acc0); atomicAdd(av + 64, acc1); atomicAdd(av + 128, acc2);
    }
}

// ---------------- Kernel C: linear_2 + self-connection + output ----------------
__global__ __launch_bounds__(256) void k_out(
    const float* __restrict__ node_s, const float* __restrict__ node_v,
    const float* __restrict__ attrs,
    const float* __restrict__ agg_s, const float* __restrict__ agg_v,
    const float* __restrict__ W2s, const float* __restrict__ W2v,
    const float* __restrict__ Wscs, const float* __restrict__ Wscv,
    float* __restrict__ out, int N)
{
    __shared__ float sW2s[2048], sW2v[2048], sCs[8192], sCv[8192];
    for (int i = threadIdx.x; i < 2048; i += 256) {
        sW2s[i] = W2s[i] * INV_2M_DEG;
        sW2v[i] = W2v[i] * INV_2M_DEG;
    }
    for (int i = threadIdx.x; i < 8192; i += 256) {
        sCs[i] = Wscs[i] * INV_FAN;
        sCv[i] = Wscv[i] * INV_FAN;
    }
    __syncthreads();
    int j = threadIdx.x & 31;
    int n = blockIdx.x * 8 + (threadIdx.x >> 5);
    if (n >= N) return;

    float at[8];
    #pragma unroll
    for (int a = 0; a < 8; ++a) at[a] = attrs[(size_t)n * 8 + a];

    float os = 0.f, o0 = 0.f, o1 = 0.f, o2 = 0.f;
    const float* ags = agg_s + (size_t)n * 64;
    const float* agv = agg_v + (size_t)n * 192;
    #pragma unroll
    for (int u = 0; u < 64; ++u) {
        float w2s = sW2s[u * 32 + j];
        float w2v = sW2v[u * 32 + j];
        os = fmaf(ags[u], w2s, os);
        o0 = fmaf(agv[u], w2v, o0);
        o1 = fmaf(agv[64 + u], w2v, o1);
        o2 = fmaf(agv[128 + u], w2v, o2);
    }

    const float* sn = node_s + (size_t)n * 32;
    const float* vn = node_v + (size_t)n * 96;
    #pragma unroll 4
    for (int u = 0; u < 32; ++u) {
        float su = sn[u];
        float v0 = vn[u * 3], v1 = vn[u * 3 + 1], v2 = vn[u * 3 + 2];
        #pragma unroll
        for (int a = 0; a < 8; ++a) {
            float ca = at[a];
            float wcs = sCs[(u * 8 + a) * 32 + j];
            float wcv = sCv[(u * 8 + a) * 32 + j];
            os = fmaf(su * ca, wcs, os);
            float t = ca * wcv;
            o0 = fmaf(v0, t, o0);
            o1 = fmaf(v1, t, o1);
            o2 = fmaf(v2, t, o2);
        }
    }

    float* op = out + (size_t)n * 128;
    op[j] = os;
    op[32 + j * 3 + 0] = o0;
    op[32 + j * 3 + 1] = o1;
    op[32 + j * 3 + 2] = o2;
}

extern "C" void kernel_launch(void* const* d_in, const int* in_sizes, int n_in,
                              void* d_out, int out_size, void* d_ws, size_t ws_size,
                              hipStream_t stream)
{
    const float* node_s = (const float*)d_in[0];
    const float* node_v = (const float*)d_in[1];
    const float* attrs  = (const float*)d_in[2];
    const float* emb    = (const float*)d_in[3];
    const float* y0     = (const float*)d_in[4];
    const float* y1     = (const float*)d_in[5];
    const int*   eidx   = (const int*)d_in[6];
    const float* W1s  = (const float*)d_in[7];
    const float* W1v  = (const float*)d_in[8];
    const float* Wr1  = (const float*)d_in[9];
    const float* Wr2  = (const float*)d_in[10];
    const float* W2s  = (const float*)d_in[11];
    const float* W2v  = (const float*)d_in[12];
    const float* Wscs = (const float*)d_in[13];
    const float* Wscv = (const float*)d_in[14];

    int N = in_sizes[0] / 32;   // 20000
    int E = in_sizes[3] / 16;   // 640000

    float* s_ws  = (float*)d_ws;                       // N*32
    float* v_ws  = s_ws + (size_t)N * 32;              // N*96
    float* agg_s = v_ws + (size_t)N * 96;              // N*64
    float* agg_v = agg_s + (size_t)N * 64;             // N*192
    float4* pk   = (float4*)(agg_v + (size_t)N * 192); // E float4
    int* count   = (int*)(pk + (size_t)E);             // N
    int* row_off = count + N;                          // N+1
    int* cursor  = row_off + (N + 1);                  // N
    int* elist   = cursor + N;                         // E
    int* srcs    = elist + E;                          // E
    int* dsts    = srcs + E;                           // E

    hipMemsetAsync(count, 0, (size_t)N * sizeof(int), stream);
    hipMemsetAsync(agg_s, 0, (size_t)N * 256 * sizeof(float), stream);

    int nblin = (N + 7) / 8;
    int nbhist = (E + 255) / 256;
    k_lin1h<<<dim3(nblin + nbhist), dim3(256), 0, stream>>>(node_s, node_v, W1s, W1v,
                                                            s_ws, v_ws, N, eidx, count, E, nblin);
    k_scan<<<dim3(1), dim3(1024), 0, stream>>>(count, row_off, cursor, N);
    k_fill<<<dim3((E + 255) / 256), dim3(256), 0, stream>>>(eidx, y0, y1, cursor,
                                                            elist, pk, srcs, dsts, E);
    k_fused<<<dim3((E + 255) / 256), dim3(256), 0, stream>>>(emb, elist, srcs, dsts, pk,
                                                             Wr1, Wr2, s_ws, v_ws,
                                                             agg_s, agg_v, E);
    k_out<<<dim3((N + 7) / 8), dim3(256), 0, stream>>>(node_s, node_v, attrs, agg_s, agg_v,
                                                       W2s, W2v, Wscs, Wscv, (float*)d_out, N);
}

// Round 7
// 419.084 us; speedup vs baseline: 2.1051x; 1.0276x over previous
//
#include <hip/hip_runtime.h>
#include <math.h>

typedef short bf16x8 __attribute__((ext_vector_type(8)));
typedef short short2v __attribute__((ext_vector_type(2)));
typedef float f32x4 __attribute__((ext_vector_type(4)));

__device__ __forceinline__ float sspf(float x) {
    return __logf(1.0f + __expf(x)) - 0.6931471805599453f;
}
__device__ __forceinline__ short f2b(float f) {
    union { float f; unsigned u; } c; c.f = f;
    unsigned r = c.u + 0x7fff + ((c.u >> 16) & 1);
    return (short)(r >> 16);
}
__device__ __forceinline__ float b2f(short s) {
    union { unsigned u; float f; } c; c.u = ((unsigned)(unsigned short)s) << 16;
    return c.f;
}
__device__ __forceinline__ int rlanei(int v, int l) {
    return __builtin_amdgcn_readlane(v, l);
}
__device__ __forceinline__ float rlanef(float v, int l) {
    return __uint_as_float(__builtin_amdgcn_readlane(__float_as_uint(v), l));
}

constexpr float INV_M      = 0.17677669529663687f;   // 1/sqrt(32)
constexpr float INV_R      = 0.25f;                  // 1/sqrt(16)
constexpr float INV_H      = 0.125f;                 // 1/sqrt(64)
constexpr float INV_2M_DEG = 0.125f * 0.17677669529663687f; // 1/sqrt(64)*1/sqrt(32)
constexpr float INV_FAN    = 0.0625f;                // 1/sqrt(32*8)
constexpr float INV_SQRT3  = 0.5773502691896258f;

// ---------- Kernel A: linear_1 + edge histogram + agg zero-fill (3-way grid split) ----------
__global__ __launch_bounds__(256) void k_lin1h(
    const float* __restrict__ node_s, const float* __restrict__ node_v,
    const float* __restrict__ W1s, const float* __restrict__ W1v,
    float* __restrict__ s_ws, float* __restrict__ v_ws, int N,
    const int* __restrict__ eidx, int* __restrict__ count, int E,
    float4* __restrict__ aggz, int nagg4, int nblin, int nbhist)
{
    int b = blockIdx.x;
    if (b >= nblin + nbhist) {
        int idx = (b - nblin - nbhist) * 256 + threadIdx.x;
        if (idx < nagg4) aggz[idx] = make_float4(0.f, 0.f, 0.f, 0.f);
        return;
    }
    if (b >= nblin) {
        int e = (b - nblin) * 256 + threadIdx.x;
        if (e < E) atomicAdd(&count[eidx[E + e]], 1);
        return;
    }
    __shared__ float sWs[1024], sWv[1024];
    for (int i = threadIdx.x; i < 1024; i += 256) {
        sWs[i] = W1s[i] * INV_M;
        sWv[i] = W1v[i] * INV_M;
    }
    __syncthreads();
    int j = threadIdx.x & 31;
    int n = b * 8 + (threadIdx.x >> 5);
    if (n >= N) return;
    const float* ss = node_s + (size_t)n * 32;
    const float* vv = node_v + (size_t)n * 96;
    float as = 0.f, a0 = 0.f, a1 = 0.f, a2 = 0.f;
    #pragma unroll
    for (int u = 0; u < 32; ++u) {
        float ws_ = sWs[u * 32 + j];
        float wv_ = sWv[u * 32 + j];
        as = fmaf(ss[u], ws_, as);
        a0 = fmaf(vv[u * 3 + 0], wv_, a0);
        a1 = fmaf(vv[u * 3 + 1], wv_, a1);
        a2 = fmaf(vv[u * 3 + 2], wv_, a2);
    }
    s_ws[(size_t)n * 32 + j] = as;
    v_ws[(size_t)n * 96 + j] = a0;
    v_ws[(size_t)n * 96 + 32 + j] = a1;
    v_ws[(size_t)n * 96 + 64 + j] = a2;
}

// one block of 1024 threads: exclusive scan of count -> cursor
__global__ __launch_bounds__(1024) void k_scan(
    const int* __restrict__ count, int* __restrict__ cursor, int N)
{
    __shared__ int wsum[16], woff[16];
    int tid = threadIdx.x;
    int per = (N + 1023) / 1024;
    int base = tid * per;
    int lim = min(N, base + per);
    int s = 0;
    for (int i = base; i < lim; ++i) s += count[i];
    int lane = tid & 63, wv = tid >> 6;
    int x = s;
    #pragma unroll
    for (int off = 1; off < 64; off <<= 1) {
        int y = __shfl_up(x, off, 64);
        if (lane >= off) x += y;
    }
    if (lane == 63) wsum[wv] = x;
    __syncthreads();
    if (wv == 0 && lane < 16) {
        int t = wsum[lane];
        int xx = t;
        #pragma unroll
        for (int off = 1; off < 16; off <<= 1) {
            int y = __shfl_up(xx, off, 64);
            if (lane >= off) xx += y;
        }
        woff[lane] = xx - t;
    }
    __syncthreads();
    int run = x - s + woff[wv];
    for (int i = base; i < lim; ++i) {
        int c = count[i];
        cursor[i] = run;
        run += c;
    }
}

// CSR fill: single 8B packed {e, dst} scatter per edge
__global__ __launch_bounds__(256) void k_fill(
    const int* __restrict__ eidx, int* __restrict__ cursor,
    int2* __restrict__ epair, int E)
{
    int e = blockIdx.x * 256 + threadIdx.x;
    if (e < E) {
        int d = eidx[E + e];
        int slot = atomicAdd(&cursor[d], 1);
        epair[slot] = make_int2(e, d);
    }
}

// ---------------- Fused: MFMA radial MLP + CG TP + segmented accumulate ----------------
// Block = 4 waves; wave owns 64 consecutive CSR slots, 4 chunks of 16.
// Per chunk, lane (q,lm): myep = epair[chunk_base + lm] -> e, dst.
//   meta: lanes 0-15 carry dst, 16-31 carry src (gather eidx[e]).
//   pkm:  q<3 -> y1[e*3+q], q==3 -> y0[e]  (same rlane layout as before).
// w tile permuted [A|B][c'][m] stride 18 halves, conflict-free, no TP shuffles.
// NOTE: wl/hl stores MUST stay short-element typed (TBAA; unsigned-punned store
// miscompiled in round 5 — reads hoisted past writes).
__global__ __launch_bounds__(256) void k_fused(
    const float* __restrict__ emb, const int2* __restrict__ epair,
    const int* __restrict__ eidx, const float* __restrict__ y0v,
    const float* __restrict__ y1,
    const float* __restrict__ Wr1, const float* __restrict__ Wr2,
    const float* __restrict__ s_ws, const float* __restrict__ v_ws,
    float* __restrict__ agg_s, float* __restrict__ agg_v, int E)
{
    __shared__ short sW1[4 * 512];          // layer1 B frags (4 KB)
    __shared__ short hbuf[4][16 * 72];      // per-wave h tile [m][hid]
    __shared__ short wtl[4][2 * 64 * 18];   // per-wave w tiles [A|B][c'][m]

    int tid = threadIdx.x;
    {   // stage Wr1 fragments (K padded 16->32 with zeros)
        int f = tid >> 6, ln = tid & 63;
        int qq = ln >> 4, lmm = ln & 15;
        short* d8 = &sW1[(f * 64 + ln) * 8];
        #pragma unroll
        for (int j = 0; j < 8; ++j) {
            int k = qq * 8 + j;
            d8[j] = (k < 16) ? f2b(Wr1[k * 64 + f * 16 + lmm] * INV_R) : (short)0;
        }
    }
    __syncthreads();

    int lane = tid & 63, wv = tid >> 6;
    int q = lane >> 4, lm = lane & 15;
    int u = lane & 31;
    bool low = (lane < 32);

    // Wr2 fragments in VGPRs
    bf16x8 wr2f[16];
    #pragma unroll
    for (int nt = 0; nt < 8; ++nt) {
        #pragma unroll
        for (int kc = 0; kc < 2; ++kc) {
            #pragma unroll
            for (int j = 0; j < 8; ++j) {
                int k = kc * 32 + q * 8 + j;
                wr2f[nt * 2 + kc][j] = f2b(Wr2[k * 128 + nt * 16 + lm] * INV_H);
            }
        }
    }

    short* hl = hbuf[wv];
    short* wl = wtl[wv];

    int base = blockIdx.x * 256 + wv * 64;
    if (base >= E) return;

    // preload chunk-0 pair + emb
    int2 nep = epair[min(base + lm, E - 1)];
    float4 pa = make_float4(0.f, 0.f, 0.f, 0.f);
    float4 pb = make_float4(0.f, 0.f, 0.f, 0.f);
    if (q < 2) {
        const float* ep = emb + (size_t)nep.x * 16 + q * 8;
        pa = *(const float4*)ep;
        pb = *(const float4*)(ep + 4);
    }

    float accs = 0.f, acc0 = 0.f, acc1 = 0.f, acc2 = 0.f;
    int cur = -1;

    for (int ch = 0; ch < 4; ++ch) {
        int cb = base + ch * 16;
        int2 myep = nep;

        // per-chunk metadata (issued early; consumed in TP)
        int srcv = 0;
        if (lane >= 16 && lane < 32) srcv = eidx[myep.x];
        int meta = (lane < 16) ? myep.y : srcv;
        float pkm = (q < 3) ? y1[(size_t)myep.x * 3 + q] : y0v[myep.x];

        // pack A fragment for layer 1
        bf16x8 af = (bf16x8){0, 0, 0, 0, 0, 0, 0, 0};
        if (q < 2) {
            af[0] = f2b(pa.x); af[1] = f2b(pa.y); af[2] = f2b(pa.z); af[3] = f2b(pa.w);
            af[4] = f2b(pb.x); af[5] = f2b(pb.y); af[6] = f2b(pb.z); af[7] = f2b(pb.w);
        }
        // prefetch next chunk's pair + emb
        if (ch < 3) {
            nep = epair[min(cb + 16 + lm, E - 1)];
            if (q < 2) {
                const float* ep = emb + (size_t)nep.x * 16 + q * 8;
                pa = *(const float4*)ep;
                pb = *(const float4*)(ep + 4);
            }
        }

        // ---- layer 1: 4 MFMA -> hbuf ----
        #pragma unroll
        for (int nt = 0; nt < 4; ++nt) {
            bf16x8 bf = *(const bf16x8*)&sW1[(nt * 64 + lane) * 8];
            f32x4 x = __builtin_amdgcn_mfma_f32_16x16x32_bf16(
                af, bf, (f32x4){0.f, 0.f, 0.f, 0.f}, 0, 0, 0);
            #pragma unroll
            for (int r = 0; r < 4; ++r)
                hl[(q * 4 + r) * 72 + nt * 16 + lm] = f2b(sspf(x[r]));
        }

        // ---- layer 2: 16 MFMA -> permuted w tile ----
        bf16x8 ha = *(const bf16x8*)&hl[lm * 72 + q * 8];
        bf16x8 hb = *(const bf16x8*)&hl[lm * 72 + 32 + q * 8];
        #pragma unroll
        for (int nt = 0; nt < 8; ++nt) {
            f32x4 acc = __builtin_amdgcn_mfma_f32_16x16x32_bf16(
                ha, wr2f[nt * 2], (f32x4){0.f, 0.f, 0.f, 0.f}, 0, 0, 0);
            acc = __builtin_amdgcn_mfma_f32_16x16x32_bf16(hb, wr2f[nt * 2 + 1], acc, 0, 0, 0);
            int cp = (nt & 1) * 16 + lm + ((nt >> 2) & 1) * 32;   // c' row
            int half = (nt >> 1) & 1;                             // 0 = A, 1 = B
            short* wp = &wl[half * 1152 + cp * 18 + q * 4];
            short2v p01 = {f2b(acc[0]), f2b(acc[1])};
            short2v p23 = {f2b(acc[2]), f2b(acc[3])};
            *(short2v*)&wp[0] = p01;
            *(short2v*)&wp[2] = p23;
        }

        // ---- TP + segmented accumulation, 4-deep gather pipeline ----
        float pse[4], pvx[4], pvy[4], pvz[4];
        #pragma unroll
        for (int k = 0; k < 4; ++k) {
            int sr = rlanei(meta, 16 + k);
            const float* sp = s_ws + (size_t)sr * 32;
            const float* vp = v_ws + (size_t)sr * 96;
            pse[k] = sp[u]; pvx[k] = vp[u]; pvy[k] = vp[32 + u]; pvz[k] = vp[64 + u];
        }
        #pragma unroll
        for (int i = 0; i < 16; ++i) {
            float se = pse[i & 3], vx = pvx[i & 3], vy = pvy[i & 3], vz = pvz[i & 3];
            if (i + 4 < 16) {
                int sr = rlanei(meta, 16 + i + 4);
                const float* sp = s_ws + (size_t)sr * 32;
                const float* vp = v_ws + (size_t)sr * 96;
                pse[(i + 4) & 3] = sp[u]; pvx[(i + 4) & 3] = vp[u];
                pvy[(i + 4) & 3] = vp[32 + u]; pvz[(i + 4) & 3] = vp[64 + u];
            }
            int d = rlanei(meta, i);
            if (d != cur) {
                if (cur >= 0) {
                    atomicAdd(&agg_s[(size_t)cur * 64 + lane], accs);
                    float* av = &agg_v[(size_t)cur * 192 + lane];
                    atomicAdd(av, acc0); atomicAdd(av + 64, acc1); atomicAdd(av + 128, acc2);
                }
                accs = acc0 = acc1 = acc2 = 0.f;
                cur = d;
            }
            float la = b2f(wl[lane * 18 + i]);            // low: w1[j]  high: w3[u]
            float lb = b2f(wl[1152 + lane * 18 + i]);     // low: w2[j]  high: w4[u]
            float y1x = rlanef(pkm, i);
            float y1y = rlanef(pkm, 16 + i);
            float y1z = rlanef(pkm, 32 + i);
            float y0e = rlanef(pkm, 48 + i);
            float dot = vx * y1x + vy * y1y + vz * y1z;
            accs += low ? (la * se * y0e) : (lb * dot * INV_SQRT3);
            float t = low ? (lb * se) : (la * y0e);
            acc0 = fmaf(t, low ? y1x : vx, acc0);
            acc1 = fmaf(t, low ? y1y : vy, acc1);
            acc2 = fmaf(t, low ? y1z : vz, acc2);
        }
    }
    if (cur >= 0) {
        atomicAdd(&agg_s[(size_t)cur * 64 + lane], accs);
        float* av = &agg_v[(size_t)cur * 192 + lane];
        atomicAdd(av, acc0); atomicAdd(av + 64, acc1); atomicAdd(av + 128, acc2);
    }
}

// ---------------- Kernel C: linear_2 + self-connection + output ----------------
__global__ __launch_bounds__(256) void k_out(
    const float* __restrict__ node_s, const float* __restrict__ node_v,
    const float* __restrict__ attrs,
    const float* __restrict__ agg_s, const float* __restrict__ agg_v,
    const float* __restrict__ W2s, const float* __restrict__ W2v,
    const float* __restrict__ Wscs, const float* __restrict__ Wscv,
    float* __restrict__ out, int N)
{
    __shared__ float sW2s[2048], sW2v[2048], sCs[8192], sCv[8192];
    for (int i = threadIdx.x; i < 2048; i += 256) {
        sW2s[i] = W2s[i] * INV_2M_DEG;
        sW2v[i] = W2v[i] * INV_2M_DEG;
    }
    for (int i = threadIdx.x; i < 8192; i += 256) {
        sCs[i] = Wscs[i] * INV_FAN;
        sCv[i] = Wscv[i] * INV_FAN;
    }
    __syncthreads();
    int j = threadIdx.x & 31;
    int n = blockIdx.x * 8 + (threadIdx.x >> 5);
    if (n >= N) return;

    float at[8];
    #pragma unroll
    for (int a = 0; a < 8; ++a) at[a] = attrs[(size_t)n * 8 + a];

    float os = 0.f, o0 = 0.f, o1 = 0.f, o2 = 0.f;
    const float* ags = agg_s + (size_t)n * 64;
    const float* agv = agg_v + (size_t)n * 192;
    #pragma unroll
    for (int u = 0; u < 64; ++u) {
        float w2s = sW2s[u * 32 + j];
        float w2v = sW2v[u * 32 + j];
        os = fmaf(ags[u], w2s, os);
        o0 = fmaf(agv[u], w2v, o0);
        o1 = fmaf(agv[64 + u], w2v, o1);
        o2 = fmaf(agv[128 + u], w2v, o2);
    }

    const float* sn = node_s + (size_t)n * 32;
    const float* vn = node_v + (size_t)n * 96;
    #pragma unroll 4
    for (int u = 0; u < 32; ++u) {
        float su = sn[u];
        float v0 = vn[u * 3], v1 = vn[u * 3 + 1], v2 = vn[u * 3 + 2];
        #pragma unroll
        for (int a = 0; a < 8; ++a) {
            float ca = at[a];
            float wcs = sCs[(u * 8 + a) * 32 + j];
            float wcv = sCv[(u * 8 + a) * 32 + j];
            os = fmaf(su * ca, wcs, os);
            float t = ca * wcv;
            o0 = fmaf(v0, t, o0);
            o1 = fmaf(v1, t, o1);
            o2 = fmaf(v2, t, o2);
        }
    }

    float* op = out + (size_t)n * 128;
    op[j] = os;
    op[32 + j * 3 + 0] = o0;
    op[32 + j * 3 + 1] = o1;
    op[32 + j * 3 + 2] = o2;
}

extern "C" void kernel_launch(void* const* d_in, const int* in_sizes, int n_in,
                              void* d_out, int out_size, void* d_ws, size_t ws_size,
                              hipStream_t stream)
{
    const float* node_s = (const float*)d_in[0];
    const float* node_v = (const float*)d_in[1];
    const float* attrs  = (const float*)d_in[2];
    const float* emb    = (const float*)d_in[3];
    const float* y0     = (const float*)d_in[4];
    const float* y1     = (const float*)d_in[5];
    const int*   eidx   = (const int*)d_in[6];
    const float* W1s  = (const float*)d_in[7];
    const float* W1v  = (const float*)d_in[8];
    const float* Wr1  = (const float*)d_in[9];
    const float* Wr2  = (const float*)d_in[10];
    const float* W2s  = (const float*)d_in[11];
    const float* W2v  = (const float*)d_in[12];
    const float* Wscs = (const float*)d_in[13];
    const float* Wscv = (const float*)d_in[14];

    int N = in_sizes[0] / 32;   // 20000
    int E = in_sizes[3] / 16;   // 640000

    float* s_ws  = (float*)d_ws;                       // N*32
    float* v_ws  = s_ws + (size_t)N * 32;              // N*96
    float* agg_s = v_ws + (size_t)N * 96;              // N*64
    float* agg_v = agg_s + (size_t)N * 64;             // N*192
    int* count   = (int*)(agg_v + (size_t)N * 192);    // N
    int* cursor  = count + N;                          // N
    int2* epair  = (int2*)(cursor + N);                // E (8B each)

    hipMemsetAsync(count, 0, (size_t)N * sizeof(int), stream);

    int nblin  = (N + 7) / 8;
    int nbhist = (E + 255) / 256;
    int nagg4  = N * 64;                     // N*256 floats / 4
    int nbz    = (nagg4 + 255) / 256;
    k_lin1h<<<dim3(nblin + nbhist + nbz), dim3(256), 0, stream>>>(
        node_s, node_v, W1s, W1v, s_ws, v_ws, N,
        eidx, count, E, (float4*)agg_s, nagg4, nblin, nbhist);
    k_scan<<<dim3(1), dim3(1024), 0, stream>>>(count, cursor, N);
    k_fill<<<dim3((E + 255) / 256), dim3(256), 0, stream>>>(eidx, cursor, epair, E);
    k_fused<<<dim3((E + 255) / 256), dim3(256), 0, stream>>>(emb, epair, eidx, y0, y1,
                                                             Wr1, Wr2, s_ws, v_ws,
                                                             agg_s, agg_v, E);
    k_out<<<dim3((N + 7) / 8), dim3(256), 0, stream>>>(node_s, node_v, attrs, agg_s, agg_v,
                                                       W2s, W2v, Wscs, Wscv, (float*)d_out, N);
}

// Round 8
// 376.638 us; speedup vs baseline: 2.3423x; 1.1127x over previous
//
#include <hip/hip_runtime.h>
#include <math.h>

typedef short bf16x8 __attribute__((ext_vector_type(8)));
typedef short short2v __attribute__((ext_vector_type(2)));
typedef float f32x4 __attribute__((ext_vector_type(4)));

__device__ __forceinline__ float sspf(float x) {
    return __logf(1.0f + __expf(x)) - 0.6931471805599453f;
}
__device__ __forceinline__ short f2b(float f) {
    union { float f; unsigned u; } c; c.f = f;
    unsigned r = c.u + 0x7fff + ((c.u >> 16) & 1);
    return (short)(r >> 16);
}
__device__ __forceinline__ float b2f(short s) {
    union { unsigned u; float f; } c; c.u = ((unsigned)(unsigned short)s) << 16;
    return c.f;
}
__device__ __forceinline__ int rlanei(int v, int l) {
    return __builtin_amdgcn_readlane(v, l);
}
__device__ __forceinline__ float rlanef(float v, int l) {
    return __uint_as_float(__builtin_amdgcn_readlane(__float_as_uint(v), l));
}
__device__ __forceinline__ bf16x8 pack8(float4 a, float4 b) {
    bf16x8 o;
    o[0] = f2b(a.x); o[1] = f2b(a.y); o[2] = f2b(a.z); o[3] = f2b(a.w);
    o[4] = f2b(b.x); o[5] = f2b(b.y); o[6] = f2b(b.z); o[7] = f2b(b.w);
    return o;
}

constexpr float INV_M      = 0.17677669529663687f;   // 1/sqrt(32)
constexpr float INV_R      = 0.25f;                  // 1/sqrt(16)
constexpr float INV_H      = 0.125f;                 // 1/sqrt(64)
constexpr float INV_2M_DEG = 0.125f * 0.17677669529663687f; // 1/sqrt(64)*1/sqrt(32)
constexpr float INV_FAN    = 0.0625f;                // 1/sqrt(32*8)
constexpr float INV_SQRT3  = 0.5773502691896258f;

// ---------- Kernel A: MFMA linear_1 + edge histogram + agg zero-fill (3-way grid split) ----------
// linear_1: wave per 16 nodes. A[m=lm][k=q*8+j] = node row; B frags in LDS;
// C: row(node)=q*4+r, col(channel)=nt*16+lm  (verified pattern from k_fused).
__global__ __launch_bounds__(256) void k_lin1h(
    const float* __restrict__ node_s, const float* __restrict__ node_v,
    const float* __restrict__ W1s, const float* __restrict__ W1v,
    float* __restrict__ s_ws, float* __restrict__ v_ws, int N,
    const int* __restrict__ eidx, int* __restrict__ count, int E,
    float4* __restrict__ aggz, int nagg4, int nblin, int nbhist)
{
    int b = blockIdx.x;
    int tid = threadIdx.x;
    if (b >= nblin + nbhist) {              // agg zero-fill: 1024 float4 per block
        int i0 = (b - nblin - nbhist) * 1024 + tid;
        #pragma unroll
        for (int r = 0; r < 4; ++r) {
            int idx = i0 + r * 256;
            if (idx < nagg4) aggz[idx] = make_float4(0.f, 0.f, 0.f, 0.f);
        }
        return;
    }
    if (b >= nblin) {                        // histogram
        int e = (b - nblin) * 256 + tid;
        if (e < E) atomicAdd(&count[eidx[E + e]], 1);
        return;
    }
    // stage W1s/W1v B-fragments: f=0,1 -> W1s nt=0,1 ; f=2,3 -> W1v nt=0,1
    __shared__ short sF[4 * 512];
    {
        int f = tid >> 6, ln = tid & 63;
        int q = ln >> 4, lm = ln & 15;
        int nt = f & 1;
        const float* Wp = (f < 2) ? W1s : W1v;
        short* d8 = &sF[tid * 8];
        #pragma unroll
        for (int j = 0; j < 8; ++j) {
            int k = q * 8 + j;
            d8[j] = f2b(Wp[k * 32 + nt * 16 + lm] * INV_M);
        }
    }
    __syncthreads();
    int lane = tid & 63, wv = tid >> 6;
    int q = lane >> 4, lm = lane & 15;
    int n0 = (b * 4 + wv) * 16;
    if (n0 >= N) return;                     // N = 20000 = 1250 tiles exactly
    int nr = n0 + lm;

    // A s-frag: 8 contiguous floats of node_s row
    const float* nsp = node_s + (size_t)nr * 32;
    bf16x8 as8 = pack8(*(const float4*)(nsp + q * 8), *(const float4*)(nsp + q * 8 + 4));
    #pragma unroll
    for (int nt = 0; nt < 2; ++nt) {
        bf16x8 bfr = *(const bf16x8*)&sF[(nt * 64 + lane) * 8];
        f32x4 acc = __builtin_amdgcn_mfma_f32_16x16x32_bf16(
            as8, bfr, (f32x4){0.f, 0.f, 0.f, 0.f}, 0, 0, 0);
        #pragma unroll
        for (int r = 0; r < 4; ++r)
            s_ws[(size_t)(n0 + q * 4 + r) * 32 + nt * 16 + lm] = acc[r];
    }
    // v: per component, A[k=u] = node_v[nr][u][i]
    const float* nvp = node_v + (size_t)nr * 96;
    #pragma unroll
    for (int i = 0; i < 3; ++i) {
        bf16x8 av8;
        #pragma unroll
        for (int j = 0; j < 8; ++j) av8[j] = f2b(nvp[(q * 8 + j) * 3 + i]);
        #pragma unroll
        for (int nt = 0; nt < 2; ++nt) {
            bf16x8 bfr = *(const bf16x8*)&sF[((2 + nt) * 64 + lane) * 8];
            f32x4 acc = __builtin_amdgcn_mfma_f32_16x16x32_bf16(
                av8, bfr, (f32x4){0.f, 0.f, 0.f, 0.f}, 0, 0, 0);
            #pragma unroll
            for (int r = 0; r < 4; ++r)
                v_ws[(size_t)(n0 + q * 4 + r) * 96 + i * 32 + nt * 16 + lm] = acc[r];
        }
    }
}

// one block of 1024 threads: exclusive scan of count -> cursor
__global__ __launch_bounds__(1024) void k_scan(
    const int* __restrict__ count, int* __restrict__ cursor, int N)
{
    __shared__ int wsum[16], woff[16];
    int tid = threadIdx.x;
    int per = (N + 1023) / 1024;
    int base = tid * per;
    int lim = min(N, base + per);
    int s = 0;
    for (int i = base; i < lim; ++i) s += count[i];
    int lane = tid & 63, wv = tid >> 6;
    int x = s;
    #pragma unroll
    for (int off = 1; off < 64; off <<= 1) {
        int y = __shfl_up(x, off, 64);
        if (lane >= off) x += y;
    }
    if (lane == 63) wsum[wv] = x;
    __syncthreads();
    if (wv == 0 && lane < 16) {
        int t = wsum[lane];
        int xx = t;
        #pragma unroll
        for (int off = 1; off < 16; off <<= 1) {
            int y = __shfl_up(xx, off, 64);
            if (lane >= off) xx += y;
        }
        woff[lane] = xx - t;
    }
    __syncthreads();
    int run = x - s + woff[wv];
    for (int i = base; i < lim; ++i) {
        int c = count[i];
        cursor[i] = run;
        run += c;
    }
}

// CSR fill: single 8B packed {e, dst} scatter per edge
__global__ __launch_bounds__(256) void k_fill(
    const int* __restrict__ eidx, int* __restrict__ cursor,
    int2* __restrict__ epair, int E)
{
    int e = blockIdx.x * 256 + threadIdx.x;
    if (e < E) {
        int d = eidx[E + e];
        int slot = atomicAdd(&cursor[d], 1);
        epair[slot] = make_int2(e, d);
    }
}

// ---------------- Fused: MFMA radial MLP + CG TP + segmented accumulate ----------------
// (unchanged from round 7 — measured 147 us)
// NOTE: wl/hl stores MUST stay short-element typed (TBAA; unsigned-punned store
// miscompiled in round 5 — reads hoisted past writes).
__global__ __launch_bounds__(256) void k_fused(
    const float* __restrict__ emb, const int2* __restrict__ epair,
    const int* __restrict__ eidx, const float* __restrict__ y0v,
    const float* __restrict__ y1,
    const float* __restrict__ Wr1, const float* __restrict__ Wr2,
    const float* __restrict__ s_ws, const float* __restrict__ v_ws,
    float* __restrict__ agg_s, float* __restrict__ agg_v, int E)
{
    __shared__ short sW1[4 * 512];          // layer1 B frags (4 KB)
    __shared__ short hbuf[4][16 * 72];      // per-wave h tile [m][hid]
    __shared__ short wtl[4][2 * 64 * 18];   // per-wave w tiles [A|B][c'][m]

    int tid = threadIdx.x;
    {   // stage Wr1 fragments (K padded 16->32 with zeros)
        int f = tid >> 6, ln = tid & 63;
        int qq = ln >> 4, lmm = ln & 15;
        short* d8 = &sW1[(f * 64 + ln) * 8];
        #pragma unroll
        for (int j = 0; j < 8; ++j) {
            int k = qq * 8 + j;
            d8[j] = (k < 16) ? f2b(Wr1[k * 64 + f * 16 + lmm] * INV_R) : (short)0;
        }
    }
    __syncthreads();

    int lane = tid & 63, wv = tid >> 6;
    int q = lane >> 4, lm = lane & 15;
    int u = lane & 31;
    bool low = (lane < 32);

    // Wr2 fragments in VGPRs
    bf16x8 wr2f[16];
    #pragma unroll
    for (int nt = 0; nt < 8; ++nt) {
        #pragma unroll
        for (int kc = 0; kc < 2; ++kc) {
            #pragma unroll
            for (int j = 0; j < 8; ++j) {
                int k = kc * 32 + q * 8 + j;
                wr2f[nt * 2 + kc][j] = f2b(Wr2[k * 128 + nt * 16 + lm] * INV_H);
            }
        }
    }

    short* hl = hbuf[wv];
    short* wl = wtl[wv];

    int base = blockIdx.x * 256 + wv * 64;
    if (base >= E) return;

    int2 nep = epair[min(base + lm, E - 1)];
    float4 pa = make_float4(0.f, 0.f, 0.f, 0.f);
    float4 pb = make_float4(0.f, 0.f, 0.f, 0.f);
    if (q < 2) {
        const float* ep = emb + (size_t)nep.x * 16 + q * 8;
        pa = *(const float4*)ep;
        pb = *(const float4*)(ep + 4);
    }

    float accs = 0.f, acc0 = 0.f, acc1 = 0.f, acc2 = 0.f;
    int cur = -1;

    for (int ch = 0; ch < 4; ++ch) {
        int cb = base + ch * 16;
        int2 myep = nep;

        int srcv = 0;
        if (lane >= 16 && lane < 32) srcv = eidx[myep.x];
        int meta = (lane < 16) ? myep.y : srcv;
        float pkm = (q < 3) ? y1[(size_t)myep.x * 3 + q] : y0v[myep.x];

        bf16x8 af = (bf16x8){0, 0, 0, 0, 0, 0, 0, 0};
        if (q < 2) af = pack8(pa, pb);
        if (ch < 3) {
            nep = epair[min(cb + 16 + lm, E - 1)];
            if (q < 2) {
                const float* ep = emb + (size_t)nep.x * 16 + q * 8;
                pa = *(const float4*)ep;
                pb = *(const float4*)(ep + 4);
            }
        }

        // ---- layer 1: 4 MFMA -> hbuf ----
        #pragma unroll
        for (int nt = 0; nt < 4; ++nt) {
            bf16x8 bfr = *(const bf16x8*)&sW1[(nt * 64 + lane) * 8];
            f32x4 x = __builtin_amdgcn_mfma_f32_16x16x32_bf16(
                af, bfr, (f32x4){0.f, 0.f, 0.f, 0.f}, 0, 0, 0);
            #pragma unroll
            for (int r = 0; r < 4; ++r)
                hl[(q * 4 + r) * 72 + nt * 16 + lm] = f2b(sspf(x[r]));
        }

        // ---- layer 2: 16 MFMA -> permuted w tile ----
        bf16x8 ha = *(const bf16x8*)&hl[lm * 72 + q * 8];
        bf16x8 hb = *(const bf16x8*)&hl[lm * 72 + 32 + q * 8];
        #pragma unroll
        for (int nt = 0; nt < 8; ++nt) {
            f32x4 acc = __builtin_amdgcn_mfma_f32_16x16x32_bf16(
                ha, wr2f[nt * 2], (f32x4){0.f, 0.f, 0.f, 0.f}, 0, 0, 0);
            acc = __builtin_amdgcn_mfma_f32_16x16x32_bf16(hb, wr2f[nt * 2 + 1], acc, 0, 0, 0);
            int cp = (nt & 1) * 16 + lm + ((nt >> 2) & 1) * 32;
            int half = (nt >> 1) & 1;
            short* wp = &wl[half * 1152 + cp * 18 + q * 4];
            short2v p01 = {f2b(acc[0]), f2b(acc[1])};
            short2v p23 = {f2b(acc[2]), f2b(acc[3])};
            *(short2v*)&wp[0] = p01;
            *(short2v*)&wp[2] = p23;
        }

        // ---- TP + segmented accumulation, 4-deep gather pipeline ----
        float pse[4], pvx[4], pvy[4], pvz[4];
        #pragma unroll
        for (int k = 0; k < 4; ++k) {
            int sr = rlanei(meta, 16 + k);
            const float* sp = s_ws + (size_t)sr * 32;
            const float* vp = v_ws + (size_t)sr * 96;
            pse[k] = sp[u]; pvx[k] = vp[u]; pvy[k] = vp[32 + u]; pvz[k] = vp[64 + u];
        }
        #pragma unroll
        for (int i = 0; i < 16; ++i) {
            float se = pse[i & 3], vx = pvx[i & 3], vy = pvy[i & 3], vz = pvz[i & 3];
            if (i + 4 < 16) {
                int sr = rlanei(meta, 16 + i + 4);
                const float* sp = s_ws + (size_t)sr * 32;
                const float* vp = v_ws + (size_t)sr * 96;
                pse[(i + 4) & 3] = sp[u]; pvx[(i + 4) & 3] = vp[u];
                pvy[(i + 4) & 3] = vp[32 + u]; pvz[(i + 4) & 3] = vp[64 + u];
            }
            int d = rlanei(meta, i);
            if (d != cur) {
                if (cur >= 0) {
                    atomicAdd(&agg_s[(size_t)cur * 64 + lane], accs);
                    float* av = &agg_v[(size_t)cur * 192 + lane];
                    atomicAdd(av, acc0); atomicAdd(av + 64, acc1); atomicAdd(av + 128, acc2);
                }
                accs = acc0 = acc1 = acc2 = 0.f;
                cur = d;
            }
            float la = b2f(wl[lane * 18 + i]);
            float lb = b2f(wl[1152 + lane * 18 + i]);
            float y1x = rlanef(pkm, i);
            float y1y = rlanef(pkm, 16 + i);
            float y1z = rlanef(pkm, 32 + i);
            float y0e = rlanef(pkm, 48 + i);
            float dot = vx * y1x + vy * y1y + vz * y1z;
            accs += low ? (la * se * y0e) : (lb * dot * INV_SQRT3);
            float t = low ? (lb * se) : (la * y0e);
            acc0 = fmaf(t, low ? y1x : vx, acc0);
            acc1 = fmaf(t, low ? y1y : vy, acc1);
            acc2 = fmaf(t, low ? y1z : vz, acc2);
        }
    }
    if (cur >= 0) {
        atomicAdd(&agg_s[(size_t)cur * 64 + lane], accs);
        float* av = &agg_v[(size_t)cur * 192 + lane];
        atomicAdd(av, acc0); atomicAdd(av + 64, acc1); atomicAdd(av + 128, acc2);
    }
}

// ---------------- Kernel C: MFMA linear_2 + self-connection + output ----------------
// Wave per 16 nodes. 40 B-fragments staged in LDS (frag f at sB[f*512 + lane*8]):
//   f 0-3   : W2s  (nt, kc)        * INV_2M_DEG   K=64
//   f 4-7   : W2v  (nt, kc)        * INV_2M_DEG   K=64
//   f 8-23  : Wscs (nt, t=0..7)    * INV_FAN      K=256, k=u*8+a
//   f 24-39 : Wscv (nt, t=0..7)    * INV_FAN      K=256, k=u*8+a
// sc A-frag at kstep t: k=t*32+q*8+j -> u=t*4+q, a=j  => node[u] * attrs[a].
__global__ __launch_bounds__(256) void k_out(
    const float* __restrict__ node_s, const float* __restrict__ node_v,
    const float* __restrict__ attrs,
    const float* __restrict__ agg_s, const float* __restrict__ agg_v,
    const float* __restrict__ W2s, const float* __restrict__ W2v,
    const float* __restrict__ Wscs, const float* __restrict__ Wscv,
    float* __restrict__ out, int N)
{
    __shared__ short sB[40 * 512];   // 40 KB
    int tid = threadIdx.x;
    for (int idx = tid; idx < 20480; idx += 256) {
        int f = idx >> 9, r = idx & 511;
        int ln = r >> 3, j = r & 7;
        int qq = ln >> 4, lmm = ln & 15;
        const float* Wp; int nt, t; float sc;
        if (f < 4)       { Wp = W2s;  nt = f >> 1;              t = f & 1; sc = INV_2M_DEG; }
        else if (f < 8)  { int g = f - 4;  Wp = W2v;  nt = g >> 1; t = g & 1; sc = INV_2M_DEG; }
        else if (f < 24) { int g = f - 8;  Wp = Wscs; nt = g >> 3; t = g & 7; sc = INV_FAN; }
        else             { int g = f - 24; Wp = Wscv; nt = g >> 3; t = g & 7; sc = INV_FAN; }
        sB[idx] = f2b(Wp[(t * 32 + qq * 8 + j) * 32 + nt * 16 + lmm] * sc);
    }
    __syncthreads();

    int lane = tid & 63, wv = tid >> 6;
    int q = lane >> 4, lm = lane & 15;
    int n0 = (blockIdx.x * 4 + wv) * 16;
    if (n0 >= N) return;                  // N = 20000 = 1250 tiles exactly
    int nr = n0 + lm;

    float4 at0 = *(const float4*)(attrs + (size_t)nr * 8);
    float4 at1 = *(const float4*)(attrs + (size_t)nr * 8 + 4);
    float at[8] = {at0.x, at0.y, at0.z, at0.w, at1.x, at1.y, at1.z, at1.w};

    // agg_s A-frags (K=64 -> 2 ksteps)
    const float* asp = agg_s + (size_t)nr * 64;
    bf16x8 aS[2];
    #pragma unroll
    for (int kc = 0; kc < 2; ++kc)
        aS[kc] = pack8(*(const float4*)(asp + kc * 32 + q * 8),
                       *(const float4*)(asp + kc * 32 + q * 8 + 4));

    // sc_s A-frags (8 ksteps): node_s[nr][t*4+q] * at[j]
    const float* nsp = node_s + (size_t)nr * 32;
    bf16x8 scs[8];
    #pragma unroll
    for (int t = 0; t < 8; ++t) {
        float nv_ = nsp[t * 4 + q];
        #pragma unroll
        for (int j = 0; j < 8; ++j) scs[t][j] = f2b(nv_ * at[j]);
    }

    // s-channel chains
    #pragma unroll
    for (int nt = 0; nt < 2; ++nt) {
        f32x4 acc = (f32x4){0.f, 0.f, 0.f, 0.f};
        acc = __builtin_amdgcn_mfma_f32_16x16x32_bf16(
            aS[0], *(const bf16x8*)&sB[(nt * 2 + 0) * 512 + lane * 8], acc, 0, 0, 0);
        acc = __builtin_amdgcn_mfma_f32_16x16x32_bf16(
            aS[1], *(const bf16x8*)&sB[(nt * 2 + 1) * 512 + lane * 8], acc, 0, 0, 0);
        #pragma unroll
        for (int t = 0; t < 8; ++t)
            acc = __builtin_amdgcn_mfma_f32_16x16x32_bf16(
                scs[t], *(const bf16x8*)&sB[(8 + nt * 8 + t) * 512 + lane * 8], acc, 0, 0, 0);
        #pragma unroll
        for (int r = 0; r < 4; ++r)
            out[(size_t)(n0 + q * 4 + r) * 128 + nt * 16 + lm] = acc[r];
    }

    // v-channel chains, per component
    const float* nvp = node_v + (size_t)nr * 96;
    const float* avp = agg_v + (size_t)nr * 192;
    #pragma unroll
    for (int i = 0; i < 3; ++i) {
        bf16x8 aV[2];
        #pragma unroll
        for (int kc = 0; kc < 2; ++kc)
            aV[kc] = pack8(*(const float4*)(avp + i * 64 + kc * 32 + q * 8),
                           *(const float4*)(avp + i * 64 + kc * 32 + q * 8 + 4));
        bf16x8 scv[8];
        #pragma unroll
        for (int t = 0; t < 8; ++t) {
            float nv_ = nvp[(t * 4 + q) * 3 + i];
            #pragma unroll
            for (int j = 0; j < 8; ++j) scv[t][j] = f2b(nv_ * at[j]);
        }
        #pragma unroll
        for (int nt = 0; nt < 2; ++nt) {
            f32x4 acc = (f32x4){0.f, 0.f, 0.f, 0.f};
            acc = __builtin_amdgcn_mfma_f32_16x16x32_bf16(
                aV[0], *(const bf16x8*)&sB[(4 + nt * 2 + 0) * 512 + lane * 8], acc, 0, 0, 0);
            acc = __builtin_amdgcn_mfma_f32_16x16x32_bf16(
                aV[1], *(const bf16x8*)&sB[(4 + nt * 2 + 1) * 512 + lane * 8], acc, 0, 0, 0);
            #pragma unroll
            for (int t = 0; t < 8; ++t)
                acc = __builtin_amdgcn_mfma_f32_16x16x32_bf16(
                    scv[t], *(const bf16x8*)&sB[(24 + nt * 8 + t) * 512 + lane * 8], acc, 0, 0, 0);
            #pragma unroll
            for (int r = 0; r < 4; ++r)
                out[(size_t)(n0 + q * 4 + r) * 128 + 32 + (nt * 16 + lm) * 3 + i] = acc[r];
        }
    }
}

extern "C" void kernel_launch(void* const* d_in, const int* in_sizes, int n_in,
                              void* d_out, int out_size, void* d_ws, size_t ws_size,
                              hipStream_t stream)
{
    const float* node_s = (const float*)d_in[0];
    const float* node_v = (const float*)d_in[1];
    const float* attrs  = (const float*)d_in[2];
    const float* emb    = (const float*)d_in[3];
    const float* y0     = (const float*)d_in[4];
    const float* y1     = (const float*)d_in[5];
    const int*   eidx   = (const int*)d_in[6];
    const float* W1s  = (const float*)d_in[7];
    const float* W1v  = (const float*)d_in[8];
    const float* Wr1  = (const float*)d_in[9];
    const float* Wr2  = (const float*)d_in[10];
    const float* W2s  = (const float*)d_in[11];
    const float* W2v  = (const float*)d_in[12];
    const float* Wscs = (const float*)d_in[13];
    const float* Wscv = (const float*)d_in[14];

    int N = in_sizes[0] / 32;   // 20000
    int E = in_sizes[3] / 16;   // 640000

    float* s_ws  = (float*)d_ws;                       // N*32
    float* v_ws  = s_ws + (size_t)N * 32;              // N*96
    float* agg_s = v_ws + (size_t)N * 96;              // N*64
    float* agg_v = agg_s + (size_t)N * 64;             // N*192
    int* count   = (int*)(agg_v + (size_t)N * 192);    // N
    int* cursor  = count + N;                          // N
    int2* epair  = (int2*)(cursor + N);                // E (8B each)

    hipMemsetAsync(count, 0, (size_t)N * sizeof(int), stream);

    int nblin  = (N + 63) / 64;              // 64 nodes (4 wave-tiles) per block
    int nbhist = (E + 255) / 256;
    int nagg4  = N * 64;                     // N*256 floats / 4
    int nbz    = (nagg4 + 1023) / 1024;
    k_lin1h<<<dim3(nblin + nbhist + nbz), dim3(256), 0, stream>>>(
        node_s, node_v, W1s, W1v, s_ws, v_ws, N,
        eidx, count, E, (float4*)agg_s, nagg4, nblin, nbhist);
    k_scan<<<dim3(1), dim3(1024), 0, stream>>>(count, cursor, N);
    k_fill<<<dim3((E + 255) / 256), dim3(256), 0, stream>>>(eidx, cursor, epair, E);
    k_fused<<<dim3((E + 255) / 256), dim3(256), 0, stream>>>(emb, epair, eidx, y0, y1,
                                                             Wr1, Wr2, s_ws, v_ws,
                                                             agg_s, agg_v, E);
    k_out<<<dim3((N + 63) / 64), dim3(256), 0, stream>>>(node_s, node_v, attrs, agg_s, agg_v,
                                                         W2s, W2v, Wscs, Wscv, (float*)d_out, N);
}

// Round 9
// 371.910 us; speedup vs baseline: 2.3721x; 1.0127x over previous
//
#include <hip/hip_runtime.h>
#include <math.h>

typedef short bf16x8 __attribute__((ext_vector_type(8)));
typedef short short2v __attribute__((ext_vector_type(2)));
typedef short short4v __attribute__((ext_vector_type(4)));
typedef float f32x4 __attribute__((ext_vector_type(4)));

__device__ __forceinline__ float sspf(float x) {
    return __logf(1.0f + __expf(x)) - 0.6931471805599453f;
}
__device__ __forceinline__ short f2b(float f) {
    union { float f; unsigned u; } c; c.f = f;
    unsigned r = c.u + 0x7fff + ((c.u >> 16) & 1);
    return (short)(r >> 16);
}
__device__ __forceinline__ float b2f(short s) {
    union { unsigned u; float f; } c; c.u = ((unsigned)(unsigned short)s) << 16;
    return c.f;
}
__device__ __forceinline__ int rlanei(int v, int l) {
    return __builtin_amdgcn_readlane(v, l);
}
__device__ __forceinline__ float rlanef(float v, int l) {
    return __uint_as_float(__builtin_amdgcn_readlane(__float_as_uint(v), l));
}
__device__ __forceinline__ bf16x8 pack8(float4 a, float4 b) {
    bf16x8 o;
    o[0] = f2b(a.x); o[1] = f2b(a.y); o[2] = f2b(a.z); o[3] = f2b(a.w);
    o[4] = f2b(b.x); o[5] = f2b(b.y); o[6] = f2b(b.z); o[7] = f2b(b.w);
    return o;
}

constexpr float INV_M      = 0.17677669529663687f;   // 1/sqrt(32)
constexpr float INV_R      = 0.25f;                  // 1/sqrt(16)
constexpr float INV_H      = 0.125f;                 // 1/sqrt(64)
constexpr float INV_2M_DEG = 0.125f * 0.17677669529663687f; // 1/sqrt(64)*1/sqrt(32)
constexpr float INV_FAN    = 0.0625f;                // 1/sqrt(32*8)
constexpr float INV_SQRT3  = 0.5773502691896258f;

// ---------- Kernel A: MFMA linear_1 + edge histogram + agg zero-fill (3-way grid split) ----------
// linear_1 result stored PACKED bf16: feat[node][chan] = {s, vx, vy, vz} (8B) so the
// edge kernel's per-slot gather is ONE dwordx2 per lane (256B/edge instead of 512B).
__global__ __launch_bounds__(256) void k_lin1h(
    const float* __restrict__ node_s, const float* __restrict__ node_v,
    const float* __restrict__ W1s, const float* __restrict__ W1v,
    short* __restrict__ feat, int N,
    const int* __restrict__ eidx, int* __restrict__ count, int E,
    float4* __restrict__ aggz, int nagg4, int nblin, int nbhist)
{
    int b = blockIdx.x;
    int tid = threadIdx.x;
    if (b >= nblin + nbhist) {              // agg zero-fill: 1024 float4 per block
        int i0 = (b - nblin - nbhist) * 1024 + tid;
        #pragma unroll
        for (int r = 0; r < 4; ++r) {
            int idx = i0 + r * 256;
            if (idx < nagg4) aggz[idx] = make_float4(0.f, 0.f, 0.f, 0.f);
        }
        return;
    }
    if (b >= nblin) {                        // histogram
        int e = (b - nblin) * 256 + tid;
        if (e < E) atomicAdd(&count[eidx[E + e]], 1);
        return;
    }
    // stage W1s/W1v B-fragments: f=0,1 -> W1s nt=0,1 ; f=2,3 -> W1v nt=0,1
    __shared__ short sF[4 * 512];
    {
        int f = tid >> 6, ln = tid & 63;
        int q = ln >> 4, lm = ln & 15;
        int nt = f & 1;
        const float* Wp = (f < 2) ? W1s : W1v;
        short* d8 = &sF[tid * 8];
        #pragma unroll
        for (int j = 0; j < 8; ++j) {
            int k = q * 8 + j;
            d8[j] = f2b(Wp[k * 32 + nt * 16 + lm] * INV_M);
        }
    }
    __syncthreads();
    int lane = tid & 63, wv = tid >> 6;
    int q = lane >> 4, lm = lane & 15;
    int n0 = (b * 4 + wv) * 16;
    if (n0 >= N) return;                     // N = 20000 = 1250 tiles exactly
    int nr = n0 + lm;

    const float* nsp = node_s + (size_t)nr * 32;
    bf16x8 as8 = pack8(*(const float4*)(nsp + q * 8), *(const float4*)(nsp + q * 8 + 4));
    const float* nvp = node_v + (size_t)nr * 96;
    bf16x8 av8[3];
    #pragma unroll
    for (int i = 0; i < 3; ++i)
        #pragma unroll
        for (int j = 0; j < 8; ++j) av8[i][j] = f2b(nvp[(q * 8 + j) * 3 + i]);

    #pragma unroll
    for (int nt = 0; nt < 2; ++nt) {
        bf16x8 bs = *(const bf16x8*)&sF[(nt * 64 + lane) * 8];
        bf16x8 bv = *(const bf16x8*)&sF[((2 + nt) * 64 + lane) * 8];
        f32x4 sa = __builtin_amdgcn_mfma_f32_16x16x32_bf16(
            as8, bs, (f32x4){0.f, 0.f, 0.f, 0.f}, 0, 0, 0);
        f32x4 v0 = __builtin_amdgcn_mfma_f32_16x16x32_bf16(
            av8[0], bv, (f32x4){0.f, 0.f, 0.f, 0.f}, 0, 0, 0);
        f32x4 v1 = __builtin_amdgcn_mfma_f32_16x16x32_bf16(
            av8[1], bv, (f32x4){0.f, 0.f, 0.f, 0.f}, 0, 0, 0);
        f32x4 v2 = __builtin_amdgcn_mfma_f32_16x16x32_bf16(
            av8[2], bv, (f32x4){0.f, 0.f, 0.f, 0.f}, 0, 0, 0);
        #pragma unroll
        for (int r = 0; r < 4; ++r) {
            short4v o = {f2b(sa[r]), f2b(v0[r]), f2b(v1[r]), f2b(v2[r])};
            *(short4v*)&feat[(size_t)(n0 + q * 4 + r) * 128 + (nt * 16 + lm) * 4] = o;
        }
    }
}

// one block of 1024 threads: exclusive scan of count -> cursor
__global__ __launch_bounds__(1024) void k_scan(
    const int* __restrict__ count, int* __restrict__ cursor, int N)
{
    __shared__ int wsum[16], woff[16];
    int tid = threadIdx.x;
    int per = (N + 1023) / 1024;
    int base = tid * per;
    int lim = min(N, base + per);
    int s = 0;
    for (int i = base; i < lim; ++i) s += count[i];
    int lane = tid & 63, wv = tid >> 6;
    int x = s;
    #pragma unroll
    for (int off = 1; off < 64; off <<= 1) {
        int y = __shfl_up(x, off, 64);
        if (lane >= off) x += y;
    }
    if (lane == 63) wsum[wv] = x;
    __syncthreads();
    if (wv == 0 && lane < 16) {
        int t = wsum[lane];
        int xx = t;
        #pragma unroll
        for (int off = 1; off < 16; off <<= 1) {
            int y = __shfl_up(xx, off, 64);
            if (lane >= off) xx += y;
        }
        woff[lane] = xx - t;
    }
    __syncthreads();
    int run = x - s + woff[wv];
    for (int i = base; i < lim; ++i) {
        int c = count[i];
        cursor[i] = run;
        run += c;
    }
}

// CSR fill: single 8B packed {e, dst} scatter per edge
__global__ __launch_bounds__(256) void k_fill(
    const int* __restrict__ eidx, int* __restrict__ cursor,
    int2* __restrict__ epair, int E)
{
    int e = blockIdx.x * 256 + threadIdx.x;
    if (e < E) {
        int d = eidx[E + e];
        int slot = atomicAdd(&cursor[d], 1);
        epair[slot] = make_int2(e, d);
    }
}

// ---------------- Fused: MFMA radial MLP + CG TP + segmented accumulate ----------------
// Per-slot source gather is now ONE 8B load: feat[src][u] = {s, vx, vy, vz} bf16.
// NOTE: wl/hl stores MUST stay short-element typed (TBAA; unsigned-punned store
// miscompiled in round 5 — reads hoisted past writes).
__global__ __launch_bounds__(256) void k_fused(
    const float* __restrict__ emb, const int2* __restrict__ epair,
    const int* __restrict__ eidx, const float* __restrict__ y0v,
    const float* __restrict__ y1,
    const float* __restrict__ Wr1, const float* __restrict__ Wr2,
    const short* __restrict__ feat,
    float* __restrict__ agg_s, float* __restrict__ agg_v, int E)
{
    __shared__ short sW1[4 * 512];          // layer1 B frags (4 KB)
    __shared__ short hbuf[4][16 * 72];      // per-wave h tile [m][hid]
    __shared__ short wtl[4][2 * 64 * 18];   // per-wave w tiles [A|B][c'][m]

    int tid = threadIdx.x;
    {   // stage Wr1 fragments (K padded 16->32 with zeros)
        int f = tid >> 6, ln = tid & 63;
        int qq = ln >> 4, lmm = ln & 15;
        short* d8 = &sW1[(f * 64 + ln) * 8];
        #pragma unroll
        for (int j = 0; j < 8; ++j) {
            int k = qq * 8 + j;
            d8[j] = (k < 16) ? f2b(Wr1[k * 64 + f * 16 + lmm] * INV_R) : (short)0;
        }
    }
    __syncthreads();

    int lane = tid & 63, wv = tid >> 6;
    int q = lane >> 4, lm = lane & 15;
    int u = lane & 31;
    bool low = (lane < 32);

    // Wr2 fragments in VGPRs
    bf16x8 wr2f[16];
    #pragma unroll
    for (int nt = 0; nt < 8; ++nt) {
        #pragma unroll
        for (int kc = 0; kc < 2; ++kc) {
            #pragma unroll
            for (int j = 0; j < 8; ++j) {
                int k = kc * 32 + q * 8 + j;
                wr2f[nt * 2 + kc][j] = f2b(Wr2[k * 128 + nt * 16 + lm] * INV_H);
            }
        }
    }

    short* hl = hbuf[wv];
    short* wl = wtl[wv];

    int base = blockIdx.x * 256 + wv * 64;
    if (base >= E) return;

    int2 nep = epair[min(base + lm, E - 1)];
    float4 pa = make_float4(0.f, 0.f, 0.f, 0.f);
    float4 pb = make_float4(0.f, 0.f, 0.f, 0.f);
    if (q < 2) {
        const float* ep = emb + (size_t)nep.x * 16 + q * 8;
        pa = *(const float4*)ep;
        pb = *(const float4*)(ep + 4);
    }

    float accs = 0.f, acc0 = 0.f, acc1 = 0.f, acc2 = 0.f;
    int cur = -1;

    for (int ch = 0; ch < 4; ++ch) {
        int cb = base + ch * 16;
        int2 myep = nep;

        int srcv = 0;
        if (lane >= 16 && lane < 32) srcv = eidx[myep.x];
        int meta = (lane < 16) ? myep.y : srcv;
        float pkm = (q < 3) ? y1[(size_t)myep.x * 3 + q] : y0v[myep.x];

        bf16x8 af = (bf16x8){0, 0, 0, 0, 0, 0, 0, 0};
        if (q < 2) af = pack8(pa, pb);
        if (ch < 3) {
            nep = epair[min(cb + 16 + lm, E - 1)];
            if (q < 2) {
                const float* ep = emb + (size_t)nep.x * 16 + q * 8;
                pa = *(const float4*)ep;
                pb = *(const float4*)(ep + 4);
            }
        }

        // ---- layer 1: 4 MFMA -> hbuf ----
        #pragma unroll
        for (int nt = 0; nt < 4; ++nt) {
            bf16x8 bfr = *(const bf16x8*)&sW1[(nt * 64 + lane) * 8];
            f32x4 x = __builtin_amdgcn_mfma_f32_16x16x32_bf16(
                af, bfr, (f32x4){0.f, 0.f, 0.f, 0.f}, 0, 0, 0);
            #pragma unroll
            for (int r = 0; r < 4; ++r)
                hl[(q * 4 + r) * 72 + nt * 16 + lm] = f2b(sspf(x[r]));
        }

        // ---- layer 2: 16 MFMA -> permuted w tile ----
        bf16x8 ha = *(const bf16x8*)&hl[lm * 72 + q * 8];
        bf16x8 hb = *(const bf16x8*)&hl[lm * 72 + 32 + q * 8];
        #pragma unroll
        for (int nt = 0; nt < 8; ++nt) {
            f32x4 acc = __builtin_amdgcn_mfma_f32_16x16x32_bf16(
                ha, wr2f[nt * 2], (f32x4){0.f, 0.f, 0.f, 0.f}, 0, 0, 0);
            acc = __builtin_amdgcn_mfma_f32_16x16x32_bf16(hb, wr2f[nt * 2 + 1], acc, 0, 0, 0);
            int cp = (nt & 1) * 16 + lm + ((nt >> 2) & 1) * 32;
            int half = (nt >> 1) & 1;
            short* wp = &wl[half * 1152 + cp * 18 + q * 4];
            short2v p01 = {f2b(acc[0]), f2b(acc[1])};
            short2v p23 = {f2b(acc[2]), f2b(acc[3])};
            *(short2v*)&wp[0] = p01;
            *(short2v*)&wp[2] = p23;
        }

        // ---- TP + segmented accumulation, 4-deep single-load gather pipeline ----
        short4v pg[4];
        #pragma unroll
        for (int k = 0; k < 4; ++k) {
            int sr = rlanei(meta, 16 + k);
            pg[k] = *(const short4v*)&feat[(size_t)sr * 128 + u * 4];
        }
        #pragma unroll
        for (int i = 0; i < 16; ++i) {
            short4v g = pg[i & 3];
            if (i + 4 < 16) {
                int sr = rlanei(meta, 16 + i + 4);
                pg[(i + 4) & 3] = *(const short4v*)&feat[(size_t)sr * 128 + u * 4];
            }
            float se = b2f(g[0]), vx = b2f(g[1]), vy = b2f(g[2]), vz = b2f(g[3]);
            int d = rlanei(meta, i);
            if (d != cur) {
                if (cur >= 0) {
                    atomicAdd(&agg_s[(size_t)cur * 64 + lane], accs);
                    float* av = &agg_v[(size_t)cur * 192 + lane];
                    atomicAdd(av, acc0); atomicAdd(av + 64, acc1); atomicAdd(av + 128, acc2);
                }
                accs = acc0 = acc1 = acc2 = 0.f;
                cur = d;
            }
            float la = b2f(wl[lane * 18 + i]);
            float lb = b2f(wl[1152 + lane * 18 + i]);
            float y1x = rlanef(pkm, i);
            float y1y = rlanef(pkm, 16 + i);
            float y1z = rlanef(pkm, 32 + i);
            float y0e = rlanef(pkm, 48 + i);
            float dot = vx * y1x + vy * y1y + vz * y1z;
            accs += low ? (la * se * y0e) : (lb * dot * INV_SQRT3);
            float t = low ? (lb * se) : (la * y0e);
            acc0 = fmaf(t, low ? y1x : vx, acc0);
            acc1 = fmaf(t, low ? y1y : vy, acc1);
            acc2 = fmaf(t, low ? y1z : vz, acc2);
        }
    }
    if (cur >= 0) {
        atomicAdd(&agg_s[(size_t)cur * 64 + lane], accs);
        float* av = &agg_v[(size_t)cur * 192 + lane];
        atomicAdd(av, acc0); atomicAdd(av + 64, acc1); atomicAdd(av + 128, acc2);
    }
}

// ---------------- Kernel C: MFMA linear_2 + self-connection + output ----------------
__global__ __launch_bounds__(256) void k_out(
    const float* __restrict__ node_s, const float* __restrict__ node_v,
    const float* __restrict__ attrs,
    const float* __restrict__ agg_s, const float* __restrict__ agg_v,
    const float* __restrict__ W2s, const float* __restrict__ W2v,
    const float* __restrict__ Wscs, const float* __restrict__ Wscv,
    float* __restrict__ out, int N)
{
    __shared__ short sB[40 * 512];   // 40 KB
    int tid = threadIdx.x;
    for (int idx = tid; idx < 20480; idx += 256) {
        int f = idx >> 9, r = idx & 511;
        int ln = r >> 3, j = r & 7;
        int qq = ln >> 4, lmm = ln & 15;
        const float* Wp; int nt, t; float sc;
        if (f < 4)       { Wp = W2s;  nt = f >> 1;              t = f & 1; sc = INV_2M_DEG; }
        else if (f < 8)  { int g = f - 4;  Wp = W2v;  nt = g >> 1; t = g & 1; sc = INV_2M_DEG; }
        else if (f < 24) { int g = f - 8;  Wp = Wscs; nt = g >> 3; t = g & 7; sc = INV_FAN; }
        else             { int g = f - 24; Wp = Wscv; nt = g >> 3; t = g & 7; sc = INV_FAN; }
        sB[idx] = f2b(Wp[(t * 32 + qq * 8 + j) * 32 + nt * 16 + lmm] * sc);
    }
    __syncthreads();

    int lane = tid & 63, wv = tid >> 6;
    int q = lane >> 4, lm = lane & 15;
    int n0 = (blockIdx.x * 4 + wv) * 16;
    if (n0 >= N) return;
    int nr = n0 + lm;

    float4 at0 = *(const float4*)(attrs + (size_t)nr * 8);
    float4 at1 = *(const float4*)(attrs + (size_t)nr * 8 + 4);
    float at[8] = {at0.x, at0.y, at0.z, at0.w, at1.x, at1.y, at1.z, at1.w};

    const float* asp = agg_s + (size_t)nr * 64;
    bf16x8 aS[2];
    #pragma unroll
    for (int kc = 0; kc < 2; ++kc)
        aS[kc] = pack8(*(const float4*)(asp + kc * 32 + q * 8),
                       *(const float4*)(asp + kc * 32 + q * 8 + 4));

    const float* nsp = node_s + (size_t)nr * 32;
    bf16x8 scs[8];
    #pragma unroll
    for (int t = 0; t < 8; ++t) {
        float nv_ = nsp[t * 4 + q];
        #pragma unroll
        for (int j = 0; j < 8; ++j) scs[t][j] = f2b(nv_ * at[j]);
    }

    #pragma unroll
    for (int nt = 0; nt < 2; ++nt) {
        f32x4 acc = (f32x4){0.f, 0.f, 0.f, 0.f};
        acc = __builtin_amdgcn_mfma_f32_16x16x32_bf16(
            aS[0], *(const bf16x8*)&sB[(nt * 2 + 0) * 512 + lane * 8], acc, 0, 0, 0);
        acc = __builtin_amdgcn_mfma_f32_16x16x32_bf16(
            aS[1], *(const bf16x8*)&sB[(nt * 2 + 1) * 512 + lane * 8], acc, 0, 0, 0);
        #pragma unroll
        for (int t = 0; t < 8; ++t)
            acc = __builtin_amdgcn_mfma_f32_16x16x32_bf16(
                scs[t], *(const bf16x8*)&sB[(8 + nt * 8 + t) * 512 + lane * 8], acc, 0, 0, 0);
        #pragma unroll
        for (int r = 0; r < 4; ++r)
            out[(size_t)(n0 + q * 4 + r) * 128 + nt * 16 + lm] = acc[r];
    }

    const float* nvp = node_v + (size_t)nr * 96;
    const float* avp = agg_v + (size_t)nr * 192;
    #pragma unroll
    for (int i = 0; i < 3; ++i) {
        bf16x8 aV[2];
        #pragma unroll
        for (int kc = 0; kc < 2; ++kc)
            aV[kc] = pack8(*(const float4*)(avp + i * 64 + kc * 32 + q * 8),
                           *(const float4*)(avp + i * 64 + kc * 32 + q * 8 + 4));
        bf16x8 scv[8];
        #pragma unroll
        for (int t = 0; t < 8; ++t) {
            float nv_ = nvp[(t * 4 + q) * 3 + i];
            #pragma unroll
            for (int j = 0; j < 8; ++j) scv[t][j] = f2b(nv_ * at[j]);
        }
        #pragma unroll
        for (int nt = 0; nt < 2; ++nt) {
            f32x4 acc = (f32x4){0.f, 0.f, 0.f, 0.f};
            acc = __builtin_amdgcn_mfma_f32_16x16x32_bf16(
                aV[0], *(const bf16x8*)&sB[(4 + nt * 2 + 0) * 512 + lane * 8], acc, 0, 0, 0);
            acc = __builtin_amdgcn_mfma_f32_16x16x32_bf16(
                aV[1], *(const bf16x8*)&sB[(4 + nt * 2 + 1) * 512 + lane * 8], acc, 0, 0, 0);
            #pragma unroll
            for (int t = 0; t < 8; ++t)
                acc = __builtin_amdgcn_mfma_f32_16x16x32_bf16(
                    scv[t], *(const bf16x8*)&sB[(24 + nt * 8 + t) * 512 + lane * 8], acc, 0, 0, 0);
            #pragma unroll
            for (int r = 0; r < 4; ++r)
                out[(size_t)(n0 + q * 4 + r) * 128 + 32 + (nt * 16 + lm) * 3 + i] = acc[r];
        }
    }
}

extern "C" void kernel_launch(void* const* d_in, const int* in_sizes, int n_in,
                              void* d_out, int out_size, void* d_ws, size_t ws_size,
                              hipStream_t stream)
{
    const float* node_s = (const float*)d_in[0];
    const float* node_v = (const float*)d_in[1];
    const float* attrs  = (const float*)d_in[2];
    const float* emb    = (const float*)d_in[3];
    const float* y0     = (const float*)d_in[4];
    const float* y1     = (const float*)d_in[5];
    const int*   eidx   = (const int*)d_in[6];
    const float* W1s  = (const float*)d_in[7];
    const float* W1v  = (const float*)d_in[8];
    const float* Wr1  = (const float*)d_in[9];
    const float* Wr2  = (const float*)d_in[10];
    const float* W2s  = (const float*)d_in[11];
    const float* W2v  = (const float*)d_in[12];
    const float* Wscs = (const float*)d_in[13];
    const float* Wscv = (const float*)d_in[14];

    int N = in_sizes[0] / 32;   // 20000
    int E = in_sizes[3] / 16;   // 640000

    float* agg_s = (float*)d_ws;                       // N*64
    float* agg_v = agg_s + (size_t)N * 64;             // N*192
    short* feat  = (short*)(agg_v + (size_t)N * 192);  // N*128 bf16 (packed {s,vx,vy,vz})
    int* count   = (int*)(feat + (size_t)N * 128);     // N
    int* cursor  = count + N;                          // N
    int2* epair  = (int2*)(cursor + N);                // E (8B each)

    hipMemsetAsync(count, 0, (size_t)N * sizeof(int), stream);

    int nblin  = (N + 63) / 64;              // 64 nodes (4 wave-tiles) per block
    int nbhist = (E + 255) / 256;
    int nagg4  = N * 64;                     // N*256 floats / 4
    int nbz    = (nagg4 + 1023) / 1024;
    k_lin1h<<<dim3(nblin + nbhist + nbz), dim3(256), 0, stream>>>(
        node_s, node_v, W1s, W1v, feat, N,
        eidx, count, E, (float4*)agg_s, nagg4, nblin, nbhist);
    k_scan<<<dim3(1), dim3(1024), 0, stream>>>(count, cursor, N);
    k_fill<<<dim3((E + 255) / 256), dim3(256), 0, stream>>>(eidx, cursor, epair, E);
    k_fused<<<dim3((E + 255) / 256), dim3(256), 0, stream>>>(emb, epair, eidx, y0, y1,
                                                             Wr1, Wr2, feat,
                                                             agg_s, agg_v, E);
    k_out<<<dim3((N + 63) / 64), dim3(256), 0, stream>>>(node_s, node_v, attrs, agg_s, agg_v,
                                                         W2s, W2v, Wscs, Wscv, (float*)d_out, N);
}